// Round 1
// baseline (882.223 us; speedup 1.0000x reference)
//
#include <hip/hip_runtime.h>
#include <math.h>

// Problem constants (B=1, T=2048)
#define N_TOK 2048
#define C_DIM 1024
#define E_NUM 32
#define TOPKK 4
#define H_EXP 512
#define HS_SH 1024

// ---------------- Router: scores = sigmoid(x @ gate_w), top-4, normalized weights ----------------
__global__ __launch_bounds__(256) void router_kernel(
    const float* __restrict__ x, const float* __restrict__ gate_w,
    const float* __restrict__ gate_bias, int* __restrict__ topk_idx,
    float* __restrict__ topk_w)
{
    __shared__ float xs[C_DIM];
    __shared__ float part[8][E_NUM];
    __shared__ float scores[E_NUM];
    const int n = blockIdx.x;
    const int t = threadIdx.x;
    const float* xr = x + (size_t)n * C_DIM;
    for (int i = t; i < C_DIM; i += 256) xs[i] = xr[i];
    __syncthreads();
    const int e = t & 31, cp = t >> 5;
    float s = 0.f;
    for (int c = cp * 128; c < cp * 128 + 128; ++c)
        s += xs[c] * gate_w[c * E_NUM + e];
    part[cp][e] = s;
    __syncthreads();
    if (t < E_NUM) {
        float tot = 0.f;
        for (int i = 0; i < 8; ++i) tot += part[i][e];
        scores[e] = 1.f / (1.f + expf(-tot));
    }
    __syncthreads();
    if (t == 0) {
        bool used[E_NUM];
        for (int i = 0; i < E_NUM; ++i) used[i] = false;
        int idx[TOPKK]; float wv[TOPKK]; float wsum = 0.f;
        for (int k = 0; k < TOPKK; ++k) {
            float best = -INFINITY; int bi = 0;
            for (int ee = 0; ee < E_NUM; ++ee) {
                if (used[ee]) continue;
                float v = scores[ee] + gate_bias[ee];
                if (v > best) { best = v; bi = ee; }   // strict > : ties keep lowest index (top_k semantics)
            }
            used[bi] = true; idx[k] = bi; wv[k] = scores[bi]; wsum += scores[bi];
        }
        float inv = 1.0f / wsum;  // ROUTE_SCALE = 1.0
        for (int k = 0; k < TOPKK; ++k) {
            topk_idx[n * TOPKK + k] = idx[k];
            topk_w[n * TOPKK + k] = wv[k] * inv;
        }
    }
}

__global__ void zero_counts_kernel(int* __restrict__ counts)
{
    if (threadIdx.x < E_NUM) counts[threadIdx.x] = 0;
}

__global__ void count_kernel(const int* __restrict__ topk_idx, int* __restrict__ counts)
{
    int i = blockIdx.x * blockDim.x + threadIdx.x;
    if (i < N_TOK * TOPKK) atomicAdd(&counts[topk_idx[i]], 1);
}

__global__ void scan_kernel(const int* __restrict__ counts, int* __restrict__ offsets,
                            int* __restrict__ cursor)
{
    if (threadIdx.x == 0) {
        int acc = 0;
        for (int e2 = 0; e2 < E_NUM; ++e2) { offsets[e2] = acc; cursor[e2] = acc; acc += counts[e2]; }
        offsets[E_NUM] = acc;   // == N_TOK*TOPKK
    }
}

__global__ void scatter_kernel(const int* __restrict__ topk_idx, const float* __restrict__ topk_w,
                               int* __restrict__ cursor, int* __restrict__ perm_token,
                               float* __restrict__ perm_w)
{
    int i = blockIdx.x * blockDim.x + threadIdx.x;
    if (i < N_TOK * TOPKK) {
        int e2 = topk_idx[i];
        int pos = atomicAdd(&cursor[e2], 1);
        perm_token[pos] = i / TOPKK;
        perm_w[pos] = topk_w[i];
    }
}

// ---------------- Tiled fp32 GEMMs: BM=64 BN=64 BK=16, 256 threads, 4x4/thread ----------------
#define BM 64
#define BN 64
#define BK 16

__device__ __forceinline__ float silu_f(float g) { return g / (1.f + __expf(-g)); }

// Hs = swiglu(X @ Wg)  : X (2048,1024), Wg (1024,2048), Hs (2048,1024)
__global__ __launch_bounds__(256) void shared_gemm1(
    const float* __restrict__ X, const float* __restrict__ Wg, float* __restrict__ Hs)
{
    __shared__ float As[BK][BM + 4];   // +4 pad: transposed stores become 2-way (free)
    __shared__ float By[BK][BN];
    __shared__ float Bg[BK][BN];
    const int n0 = blockIdx.x * BN;
    const int m0 = blockIdx.y * BM;
    const int t = threadIdx.x;
    const int tx = t & 15, ty = t >> 4;
    const int lrow = t >> 2, lk4 = (t & 3) << 2;
    const int bk = t >> 4, bcol = (t & 15) << 2;
    float ay[4][4] = {{0.f}}, ag[4][4] = {{0.f}};
    const float* Arow = X + (size_t)(m0 + lrow) * C_DIM + lk4;
    for (int k0 = 0; k0 < C_DIM; k0 += BK) {
        float4 av = *(const float4*)(Arow + k0);
        float4 byv = *(const float4*)(Wg + (size_t)(k0 + bk) * (2 * HS_SH) + n0 + bcol);
        float4 bgv = *(const float4*)(Wg + (size_t)(k0 + bk) * (2 * HS_SH) + HS_SH + n0 + bcol);
        __syncthreads();
        As[lk4 + 0][lrow] = av.x; As[lk4 + 1][lrow] = av.y;
        As[lk4 + 2][lrow] = av.z; As[lk4 + 3][lrow] = av.w;
        *(float4*)&By[bk][bcol] = byv;
        *(float4*)&Bg[bk][bcol] = bgv;
        __syncthreads();
#pragma unroll
        for (int kk = 0; kk < BK; ++kk) {
            float a4[4], by4[4], bg4[4];
#pragma unroll
            for (int i = 0; i < 4; ++i) a4[i] = As[kk][ty * 4 + i];
#pragma unroll
            for (int j = 0; j < 4; ++j) { by4[j] = By[kk][tx * 4 + j]; bg4[j] = Bg[kk][tx * 4 + j]; }
#pragma unroll
            for (int i = 0; i < 4; ++i)
#pragma unroll
                for (int j = 0; j < 4; ++j) {
                    ay[i][j] = fmaf(a4[i], by4[j], ay[i][j]);
                    ag[i][j] = fmaf(a4[i], bg4[j], ag[i][j]);
                }
        }
    }
#pragma unroll
    for (int i = 0; i < 4; ++i) {
        float4 o;
        float* op = (float*)&o;
#pragma unroll
        for (int j = 0; j < 4; ++j) op[j] = silu_f(ag[i][j]) * ay[i][j];
        *(float4*)(Hs + (size_t)(m0 + ty * 4 + i) * HS_SH + n0 + tx * 4) = o;
    }
}

// Out = Hs @ Wd : Hs (2048,1024), Wd (1024,1024) -> initializes d_out with the shared expert
__global__ __launch_bounds__(256) void shared_gemm2(
    const float* __restrict__ Hs, const float* __restrict__ Wd, float* __restrict__ Out)
{
    __shared__ float As[BK][BM + 4];
    __shared__ float Bs[BK][BN];
    const int n0 = blockIdx.x * BN;
    const int m0 = blockIdx.y * BM;
    const int t = threadIdx.x;
    const int tx = t & 15, ty = t >> 4;
    const int lrow = t >> 2, lk4 = (t & 3) << 2;
    const int bk = t >> 4, bcol = (t & 15) << 2;
    float acc[4][4] = {{0.f}};
    const float* Arow = Hs + (size_t)(m0 + lrow) * HS_SH + lk4;
    for (int k0 = 0; k0 < HS_SH; k0 += BK) {
        float4 av = *(const float4*)(Arow + k0);
        float4 bv = *(const float4*)(Wd + (size_t)(k0 + bk) * C_DIM + n0 + bcol);
        __syncthreads();
        As[lk4 + 0][lrow] = av.x; As[lk4 + 1][lrow] = av.y;
        As[lk4 + 2][lrow] = av.z; As[lk4 + 3][lrow] = av.w;
        *(float4*)&Bs[bk][bcol] = bv;
        __syncthreads();
#pragma unroll
        for (int kk = 0; kk < BK; ++kk) {
            float a4[4], b4[4];
#pragma unroll
            for (int i = 0; i < 4; ++i) a4[i] = As[kk][ty * 4 + i];
#pragma unroll
            for (int j = 0; j < 4; ++j) b4[j] = Bs[kk][tx * 4 + j];
#pragma unroll
            for (int i = 0; i < 4; ++i)
#pragma unroll
                for (int j = 0; j < 4; ++j) acc[i][j] = fmaf(a4[i], b4[j], acc[i][j]);
        }
    }
#pragma unroll
    for (int i = 0; i < 4; ++i) {
        float4 o;
        float* op = (float*)&o;
#pragma unroll
        for (int j = 0; j < 4; ++j) op[j] = acc[i][j];
        *(float4*)(Out + (size_t)(m0 + ty * 4 + i) * C_DIM + n0 + tx * 4) = o;
    }
}

// Per-expert: He = swiglu(X[gathered] @ EWg[e]) : cols 512, K=1024
__global__ __launch_bounds__(256) void expert_gemm1(
    const float* __restrict__ X, const float* __restrict__ EWg,
    const int* __restrict__ offsets, const int* __restrict__ perm_token,
    float* __restrict__ He)
{
    const int e = blockIdx.z;
    const int base = offsets[e];
    const int cnt = offsets[e + 1] - base;
    const int m0 = blockIdx.y * BM;
    if (m0 >= cnt) return;
    const float* Wg = EWg + (size_t)e * C_DIM * (2 * H_EXP);
    const int n0 = blockIdx.x * BN;
    __shared__ float As[BK][BM + 4];
    __shared__ float By[BK][BN];
    __shared__ float Bg[BK][BN];
    const int t = threadIdx.x;
    const int tx = t & 15, ty = t >> 4;
    const int lrow = t >> 2, lk4 = (t & 3) << 2;
    const int bk = t >> 4, bcol = (t & 15) << 2;
    float ay[4][4] = {{0.f}}, ag[4][4] = {{0.f}};
    const int arow = m0 + lrow;
    const int tok = perm_token[base + (arow < cnt ? arow : 0)];
    const float* Arow = X + (size_t)tok * C_DIM + lk4;
    for (int k0 = 0; k0 < C_DIM; k0 += BK) {
        float4 av = *(const float4*)(Arow + k0);
        float4 byv = *(const float4*)(Wg + (size_t)(k0 + bk) * (2 * H_EXP) + n0 + bcol);
        float4 bgv = *(const float4*)(Wg + (size_t)(k0 + bk) * (2 * H_EXP) + H_EXP + n0 + bcol);
        __syncthreads();
        As[lk4 + 0][lrow] = av.x; As[lk4 + 1][lrow] = av.y;
        As[lk4 + 2][lrow] = av.z; As[lk4 + 3][lrow] = av.w;
        *(float4*)&By[bk][bcol] = byv;
        *(float4*)&Bg[bk][bcol] = bgv;
        __syncthreads();
#pragma unroll
        for (int kk = 0; kk < BK; ++kk) {
            float a4[4], by4[4], bg4[4];
#pragma unroll
            for (int i = 0; i < 4; ++i) a4[i] = As[kk][ty * 4 + i];
#pragma unroll
            for (int j = 0; j < 4; ++j) { by4[j] = By[kk][tx * 4 + j]; bg4[j] = Bg[kk][tx * 4 + j]; }
#pragma unroll
            for (int i = 0; i < 4; ++i)
#pragma unroll
                for (int j = 0; j < 4; ++j) {
                    ay[i][j] = fmaf(a4[i], by4[j], ay[i][j]);
                    ag[i][j] = fmaf(a4[i], bg4[j], ag[i][j]);
                }
        }
    }
#pragma unroll
    for (int i = 0; i < 4; ++i) {
        const int grow = m0 + ty * 4 + i;
        if (grow < cnt) {
            float4 o;
            float* op = (float*)&o;
#pragma unroll
            for (int j = 0; j < 4; ++j) op[j] = silu_f(ag[i][j]) * ay[i][j];
            *(float4*)(He + (size_t)(base + grow) * H_EXP + n0 + tx * 4) = o;
        }
    }
}

// Per-expert: Out[token] += w * (He @ EWd[e]) : K=512, cols 1024, atomic combine
__global__ __launch_bounds__(256) void expert_gemm2(
    const float* __restrict__ He, const float* __restrict__ EWd,
    const int* __restrict__ offsets, const int* __restrict__ perm_token,
    const float* __restrict__ perm_w, float* __restrict__ Out)
{
    const int e = blockIdx.z;
    const int base = offsets[e];
    const int cnt = offsets[e + 1] - base;
    const int m0 = blockIdx.y * BM;
    if (m0 >= cnt) return;
    const float* Wd = EWd + (size_t)e * H_EXP * C_DIM;
    const int n0 = blockIdx.x * BN;
    __shared__ float As[BK][BM + 4];
    __shared__ float Bs[BK][BN];
    const int t = threadIdx.x;
    const int tx = t & 15, ty = t >> 4;
    const int lrow = t >> 2, lk4 = (t & 3) << 2;
    const int bk = t >> 4, bcol = (t & 15) << 2;
    float acc[4][4] = {{0.f}};
    const int arow = m0 + lrow;
    const int slot = base + (arow < cnt ? arow : 0);
    const float* Arow = He + (size_t)slot * H_EXP + lk4;
    for (int k0 = 0; k0 < H_EXP; k0 += BK) {
        float4 av = *(const float4*)(Arow + k0);
        float4 bv = *(const float4*)(Wd + (size_t)(k0 + bk) * C_DIM + n0 + bcol);
        __syncthreads();
        As[lk4 + 0][lrow] = av.x; As[lk4 + 1][lrow] = av.y;
        As[lk4 + 2][lrow] = av.z; As[lk4 + 3][lrow] = av.w;
        *(float4*)&Bs[bk][bcol] = bv;
        __syncthreads();
#pragma unroll
        for (int kk = 0; kk < BK; ++kk) {
            float a4[4], b4[4];
#pragma unroll
            for (int i = 0; i < 4; ++i) a4[i] = As[kk][ty * 4 + i];
#pragma unroll
            for (int j = 0; j < 4; ++j) b4[j] = Bs[kk][tx * 4 + j];
#pragma unroll
            for (int i = 0; i < 4; ++i)
#pragma unroll
                for (int j = 0; j < 4; ++j) acc[i][j] = fmaf(a4[i], b4[j], acc[i][j]);
        }
    }
#pragma unroll
    for (int i = 0; i < 4; ++i) {
        const int grow = m0 + ty * 4 + i;
        if (grow < cnt) {
            const int tok = perm_token[base + grow];
            const float w = perm_w[base + grow];
            float* orow = Out + (size_t)tok * C_DIM + n0 + tx * 4;
#pragma unroll
            for (int j = 0; j < 4; ++j) atomicAdd(&orow[j], w * acc[i][j]);
        }
    }
}

extern "C" void kernel_launch(void* const* d_in, const int* in_sizes, int n_in,
                              void* d_out, int out_size, void* d_ws, size_t ws_size,
                              hipStream_t stream)
{
    const float* x   = (const float*)d_in[0];
    const float* gw  = (const float*)d_in[1];
    const float* gb  = (const float*)d_in[2];
    const float* sgw = (const float*)d_in[3];
    const float* sdw = (const float*)d_in[4];
    const float* egw = (const float*)d_in[5];
    const float* edw = (const float*)d_in[6];
    float* out = (float*)d_out;

    char* ws = (char*)d_ws;
    size_t off = 0;
    auto alloc = [&](size_t bytes) -> void* {
        void* p = ws + off;
        off = (off + bytes + 255) & ~(size_t)255;
        return p;
    };
    int*   topk_idx = (int*)  alloc((size_t)N_TOK * TOPKK * sizeof(int));
    float* topk_w   = (float*)alloc((size_t)N_TOK * TOPKK * sizeof(float));
    int*   counts   = (int*)  alloc(E_NUM * sizeof(int));
    int*   offsets  = (int*)  alloc((E_NUM + 1) * sizeof(int));
    int*   cursor   = (int*)  alloc(E_NUM * sizeof(int));
    int*   perm_tok = (int*)  alloc((size_t)N_TOK * TOPKK * sizeof(int));
    float* perm_w   = (float*)alloc((size_t)N_TOK * TOPKK * sizeof(float));
    float* Hs       = (float*)alloc((size_t)N_TOK * HS_SH * sizeof(float));
    float* He       = (float*)alloc((size_t)N_TOK * TOPKK * H_EXP * sizeof(float));
    (void)ws_size; (void)in_sizes; (void)n_in; (void)out_size;

    // Routing
    router_kernel<<<N_TOK, 256, 0, stream>>>(x, gw, gb, topk_idx, topk_w);
    zero_counts_kernel<<<1, 64, 0, stream>>>(counts);
    count_kernel<<<(N_TOK * TOPKK + 255) / 256, 256, 0, stream>>>(topk_idx, counts);
    scan_kernel<<<1, 64, 0, stream>>>(counts, offsets, cursor);
    scatter_kernel<<<(N_TOK * TOPKK + 255) / 256, 256, 0, stream>>>(topk_idx, topk_w, cursor,
                                                                    perm_tok, perm_w);
    // Shared expert (writes full out -> also initializes it)
    dim3 g1(HS_SH / BN, N_TOK / BM);
    shared_gemm1<<<g1, 256, 0, stream>>>(x, sgw, Hs);
    dim3 g2(C_DIM / BN, N_TOK / BM);
    shared_gemm2<<<g2, 256, 0, stream>>>(Hs, sdw, out);
    // Routed experts (grouped GEMMs; blocks beyond an expert's count exit early)
    dim3 g3(H_EXP / BN, N_TOK / BM, E_NUM);
    expert_gemm1<<<g3, 256, 0, stream>>>(x, egw, offsets, perm_tok, He);
    dim3 g4(C_DIM / BN, N_TOK / BM, E_NUM);
    expert_gemm2<<<g4, 256, 0, stream>>>(He, edw, offsets, perm_tok, perm_w, out);
}

// Round 2
// 699.430 us; speedup vs baseline: 1.2613x; 1.2613x over previous
//
#include <hip/hip_runtime.h>
#include <hip/hip_bf16.h>
#include <math.h>

// Problem constants (B=1, T=2048)
#define N_TOK 2048
#define C_DIM 1024
#define E_NUM 32
#define TOPKK 4
#define H_EXP 512
#define HS_SH 1024
#define NSLOT (N_TOK * TOPKK)   // 8192

typedef __attribute__((ext_vector_type(8))) short short8;
typedef __attribute__((ext_vector_type(4))) float f32x4;

__device__ __forceinline__ ushort f2b(float f) {
    __hip_bfloat16 h = __float2bfloat16(f);   // RNE
    return *(ushort*)&h;
}
__device__ __forceinline__ float silu_f(float g) { return g / (1.f + __expf(-g)); }

// ---------------- Router (unchanged from round 1: exact fp32, passed) ----------------
__global__ __launch_bounds__(256) void router_kernel(
    const float* __restrict__ x, const float* __restrict__ gate_w,
    const float* __restrict__ gate_bias, int* __restrict__ topk_idx,
    float* __restrict__ topk_w)
{
    __shared__ float xs[C_DIM];
    __shared__ float part[8][E_NUM];
    __shared__ float scores[E_NUM];
    const int n = blockIdx.x;
    const int t = threadIdx.x;
    const float* xr = x + (size_t)n * C_DIM;
    for (int i = t; i < C_DIM; i += 256) xs[i] = xr[i];
    __syncthreads();
    const int e = t & 31, cp = t >> 5;
    float s = 0.f;
    for (int c = cp * 128; c < cp * 128 + 128; ++c)
        s += xs[c] * gate_w[c * E_NUM + e];
    part[cp][e] = s;
    __syncthreads();
    if (t < E_NUM) {
        float tot = 0.f;
        for (int i = 0; i < 8; ++i) tot += part[i][e];
        scores[e] = 1.f / (1.f + expf(-tot));
    }
    __syncthreads();
    if (t == 0) {
        bool used[E_NUM];
        for (int i = 0; i < E_NUM; ++i) used[i] = false;
        int idx[TOPKK]; float wv[TOPKK]; float wsum = 0.f;
        for (int k = 0; k < TOPKK; ++k) {
            float best = -INFINITY; int bi = 0;
            for (int ee = 0; ee < E_NUM; ++ee) {
                if (used[ee]) continue;
                float v = scores[ee] + gate_bias[ee];
                if (v > best) { best = v; bi = ee; }
            }
            used[bi] = true; idx[k] = bi; wv[k] = scores[bi]; wsum += scores[bi];
        }
        float inv = 1.0f / wsum;
        for (int k = 0; k < TOPKK; ++k) {
            topk_idx[n * TOPKK + k] = idx[k];
            topk_w[n * TOPKK + k] = wv[k] * inv;
        }
    }
}

__global__ void zero_counts_kernel(int* __restrict__ counts)
{
    if (threadIdx.x < E_NUM) counts[threadIdx.x] = 0;
}

__global__ void count_kernel(const int* __restrict__ topk_idx, int* __restrict__ counts)
{
    int i = blockIdx.x * blockDim.x + threadIdx.x;
    if (i < NSLOT) atomicAdd(&counts[topk_idx[i]], 1);
}

__global__ void scan_kernel(const int* __restrict__ counts, int* __restrict__ offsets,
                            int* __restrict__ cursor)
{
    if (threadIdx.x == 0) {
        int acc = 0;
        for (int e2 = 0; e2 < E_NUM; ++e2) { offsets[e2] = acc; cursor[e2] = acc; acc += counts[e2]; }
        offsets[E_NUM] = acc;
    }
}

__global__ void scatter_kernel(const int* __restrict__ topk_idx, const float* __restrict__ topk_w,
                               int* __restrict__ cursor, int* __restrict__ perm_token,
                               float* __restrict__ perm_w)
{
    int i = blockIdx.x * blockDim.x + threadIdx.x;
    if (i < NSLOT) {
        int e2 = topk_idx[i];
        int pos = atomicAdd(&cursor[e2], 1);
        perm_token[pos] = i / TOPKK;
        perm_w[pos] = topk_w[i];
    }
}

// ---------------- Conversion: x (fp32) -> xb (bf16) ----------------
__global__ __launch_bounds__(256) void convert_x_kernel(const float* __restrict__ x,
                                                        ushort* __restrict__ xb)
{
    int gid = blockIdx.x * 256 + threadIdx.x;      // 2048*1024/4 threads
    const float4 v = *(const float4*)(x + (size_t)gid * 4);
    ushort4 o;
    o.x = f2b(v.x); o.y = f2b(v.y); o.z = f2b(v.z); o.w = f2b(v.w);
    *(ushort4*)(xb + (size_t)gid * 4) = o;
}

// Gather permuted token rows: Xg[slot] = xb[perm_token[slot]]
__global__ __launch_bounds__(256) void gather_kernel(const ushort* __restrict__ xb,
                                                     const int* __restrict__ perm_token,
                                                     ushort* __restrict__ Xg)
{
    const int slot = blockIdx.x;
    const int row = perm_token[slot];
    const int t = threadIdx.x;                     // 256 threads * 4 ushort = 1024
    *(ushort4*)(Xg + (size_t)slot * C_DIM + t * 4) =
        *(const ushort4*)(xb + (size_t)row * C_DIM + t * 4);
}

// ---------------- Transpose+convert weights to bf16 N'xK (B^T) layout ----------------
// PAIR_H > 0: interleave y/g columns in 16-col groups so SwiGLU pairs land in
// adjacent MFMA n-tiles (per-lane combine, no shuffle):
//   y col n (<H)  -> row 32*(n>>4) + (n&15)
//   g col n (>=H) -> row 32*((n-H)>>4) + 16 + ((n-H)&15)
template<int K, int N, int PAIR_H>
__global__ __launch_bounds__(256) void transp_conv(const float* __restrict__ in,
                                                   ushort* __restrict__ out)
{
    const float* inp = in + (size_t)blockIdx.z * K * N;
    ushort* outp = out + (size_t)blockIdx.z * K * N;
    __shared__ float T[32][33];
    const int tx = threadIdx.x, ty = threadIdx.y;      // (32, 8)
    const int n0 = blockIdx.x * 32, k0 = blockIdx.y * 32;
#pragma unroll
    for (int r = 0; r < 4; ++r)
        T[ty + r * 8][tx] = inp[(size_t)(k0 + ty + r * 8) * N + n0 + tx];
    __syncthreads();
#pragma unroll
    for (int r = 0; r < 4; ++r) {
        int n = n0 + ty + r * 8;
        int np;
        if (PAIR_H > 0)
            np = (n < PAIR_H) ? ((n >> 4) * 32 + (n & 15))
                              : (((n - PAIR_H) >> 4) * 32 + 16 + ((n - PAIR_H) & 15));
        else
            np = n;
        outp[(size_t)np * K + k0 + tx] = f2b(T[tx][ty + r * 8]);
    }
}

// ---------------- bf16 MFMA GEMM, 128x128 tile, 4 waves, 16x16x32 ----------------
// A: rows x K bf16 (row-major, k-contiguous). Bt: N' x K bf16 (B^T).
// SwiGLU variant: NP = 2*H paired columns; writes H bf16 outputs per row.
template<int K, int NP, bool EXPERT>
__global__ __launch_bounds__(256) void swiglu_mfma(
    const ushort* __restrict__ Ab, const ushort* __restrict__ Bt,
    ushort* __restrict__ Out, const int* __restrict__ offsets)
{
    constexpr int H = NP / 2;
    int base = 0, cnt = N_TOK;
    const ushort* B = Bt;
    if (EXPERT) {
        const int e = blockIdx.z;
        base = offsets[e]; cnt = offsets[e + 1] - base;
        B = Bt + (size_t)e * NP * K;
    }
    const int m0 = blockIdx.y * 128;
    if (m0 >= cnt) return;
    const int n0 = blockIdx.x * 128;
    const ushort* A = Ab + (size_t)base * K;
    ushort* O = Out + (size_t)base * H;

    __shared__ __align__(16) ushort As[128 * 72];   // +8 pad: frag reads ~2-way (free)
    __shared__ __align__(16) ushort Bs[128 * 72];

    const int t = threadIdx.x;
    const int lane = t & 63, wave = t >> 6;
    const int wr = wave >> 1, wc = wave & 1;
    const int quad = lane >> 4, l16 = lane & 15;
    const int srow = t >> 3, scol = (t & 7) * 8;

    f32x4 acc[4][4];
#pragma unroll
    for (int i = 0; i < 4; ++i)
#pragma unroll
        for (int j = 0; j < 4; ++j) acc[i][j] = (f32x4){0.f, 0.f, 0.f, 0.f};

    for (int k0 = 0; k0 < K; k0 += 64) {
        float4 a_ld[4], b_ld[4];
#pragma unroll
        for (int i = 0; i < 4; ++i) {
            const int row = srow + i * 32;
            a_ld[i] = *(const float4*)(A + (size_t)(m0 + row) * K + k0 + scol);
            b_ld[i] = *(const float4*)(B + (size_t)(n0 + row) * K + k0 + scol);
        }
        __syncthreads();
#pragma unroll
        for (int i = 0; i < 4; ++i) {
            const int row = srow + i * 32;
            *(float4*)(As + row * 72 + scol) = a_ld[i];
            *(float4*)(Bs + row * 72 + scol) = b_ld[i];
        }
        __syncthreads();
#pragma unroll
        for (int ks = 0; ks < 2; ++ks) {
            const int kk = ks * 32 + quad * 8;
            short8 af[4], bfr[4];
#pragma unroll
            for (int i = 0; i < 4; ++i) {
                af[i]  = *(const short8*)(As + (wr * 64 + i * 16 + l16) * 72 + kk);
                bfr[i] = *(const short8*)(Bs + (wc * 64 + i * 16 + l16) * 72 + kk);
            }
#pragma unroll
            for (int tm = 0; tm < 4; ++tm)
#pragma unroll
                for (int tn = 0; tn < 4; ++tn)
                    acc[tm][tn] = __builtin_amdgcn_mfma_f32_16x16x32_bf16(
                        af[tm], bfr[tn], acc[tm][tn], 0, 0, 0);
        }
    }

    // Epilogue: SwiGLU pair-combine (tn even = y, tn odd = g), LDS transpose, 16B stores
    __syncthreads();
#pragma unroll
    for (int tm = 0; tm < 4; ++tm)
#pragma unroll
        for (int p = 0; p < 2; ++p)
#pragma unroll
            for (int r = 0; r < 4; ++r) {
                const int ml = wr * 64 + tm * 16 + quad * 4 + r;
                const int hl = wc * 32 + p * 16 + l16;
                const float y = acc[tm][2 * p][r];
                const float g = acc[tm][2 * p + 1][r];
                As[ml * 72 + hl] = f2b(silu_f(g) * y);
            }
    __syncthreads();
#pragma unroll
    for (int i = 0; i < 4; ++i) {
        const int c = t + i * 256;
        const int row = c >> 3, col = (c & 7) * 8;
        if (m0 + row < cnt)
            *(float4*)(O + (size_t)(m0 + row) * H + (n0 >> 1) + col) =
                *(const float4*)(As + row * 72 + col);
    }
}

// Down-proj GEMM: N = C_DIM. Shared: plain store (initializes Out).
// Expert: scatter atomicAdd weighted by routing weight.
template<int K, bool EXPERT>
__global__ __launch_bounds__(256) void down_mfma(
    const ushort* __restrict__ Ab, const ushort* __restrict__ Bt,
    float* __restrict__ Out, const int* __restrict__ offsets,
    const int* __restrict__ perm_tok, const float* __restrict__ perm_w)
{
    int base = 0, cnt = N_TOK;
    const ushort* B = Bt;
    if (EXPERT) {
        const int e = blockIdx.z;
        base = offsets[e]; cnt = offsets[e + 1] - base;
        B = Bt + (size_t)e * C_DIM * K;
    }
    const int m0 = blockIdx.y * 128;
    if (m0 >= cnt) return;
    const int n0 = blockIdx.x * 128;
    const ushort* A = Ab + (size_t)base * K;

    __shared__ __align__(16) ushort As[128 * 72];
    __shared__ __align__(16) ushort Bs[128 * 72];

    const int t = threadIdx.x;
    const int lane = t & 63, wave = t >> 6;
    const int wr = wave >> 1, wc = wave & 1;
    const int quad = lane >> 4, l16 = lane & 15;
    const int srow = t >> 3, scol = (t & 7) * 8;

    f32x4 acc[4][4];
#pragma unroll
    for (int i = 0; i < 4; ++i)
#pragma unroll
        for (int j = 0; j < 4; ++j) acc[i][j] = (f32x4){0.f, 0.f, 0.f, 0.f};

    for (int k0 = 0; k0 < K; k0 += 64) {
        float4 a_ld[4], b_ld[4];
#pragma unroll
        for (int i = 0; i < 4; ++i) {
            const int row = srow + i * 32;
            a_ld[i] = *(const float4*)(A + (size_t)(m0 + row) * K + k0 + scol);
            b_ld[i] = *(const float4*)(B + (size_t)(n0 + row) * K + k0 + scol);
        }
        __syncthreads();
#pragma unroll
        for (int i = 0; i < 4; ++i) {
            const int row = srow + i * 32;
            *(float4*)(As + row * 72 + scol) = a_ld[i];
            *(float4*)(Bs + row * 72 + scol) = b_ld[i];
        }
        __syncthreads();
#pragma unroll
        for (int ks = 0; ks < 2; ++ks) {
            const int kk = ks * 32 + quad * 8;
            short8 af[4], bfr[4];
#pragma unroll
            for (int i = 0; i < 4; ++i) {
                af[i]  = *(const short8*)(As + (wr * 64 + i * 16 + l16) * 72 + kk);
                bfr[i] = *(const short8*)(Bs + (wc * 64 + i * 16 + l16) * 72 + kk);
            }
#pragma unroll
            for (int tm = 0; tm < 4; ++tm)
#pragma unroll
                for (int tn = 0; tn < 4; ++tn)
                    acc[tm][tn] = __builtin_amdgcn_mfma_f32_16x16x32_bf16(
                        af[tm], bfr[tn], acc[tm][tn], 0, 0, 0);
        }
    }

#pragma unroll
    for (int tm = 0; tm < 4; ++tm)
#pragma unroll
        for (int r = 0; r < 4; ++r) {
            const int grow = m0 + wr * 64 + tm * 16 + quad * 4 + r;
            if (EXPERT) {
                if (grow < cnt) {
                    const int tok = perm_tok[base + grow];
                    const float w = perm_w[base + grow];
#pragma unroll
                    for (int tn = 0; tn < 4; ++tn) {
                        const int col = n0 + wc * 64 + tn * 16 + l16;
                        atomicAdd(&Out[(size_t)tok * C_DIM + col], w * acc[tm][tn][r]);
                    }
                }
            } else {
#pragma unroll
                for (int tn = 0; tn < 4; ++tn) {
                    const int col = n0 + wc * 64 + tn * 16 + l16;
                    Out[(size_t)grow * C_DIM + col] = acc[tm][tn][r];
                }
            }
        }
}

extern "C" void kernel_launch(void* const* d_in, const int* in_sizes, int n_in,
                              void* d_out, int out_size, void* d_ws, size_t ws_size,
                              hipStream_t stream)
{
    const float* x   = (const float*)d_in[0];
    const float* gw  = (const float*)d_in[1];
    const float* gb  = (const float*)d_in[2];
    const float* sgw = (const float*)d_in[3];
    const float* sdw = (const float*)d_in[4];
    const float* egw = (const float*)d_in[5];
    const float* edw = (const float*)d_in[6];
    float* out = (float*)d_out;

    char* ws = (char*)d_ws;
    size_t off = 0;
    auto alloc = [&](size_t bytes) -> void* {
        void* p = ws + off;
        off = (off + bytes + 255) & ~(size_t)255;
        return p;
    };
    int*    topk_idx = (int*)   alloc((size_t)NSLOT * sizeof(int));
    float*  topk_w   = (float*) alloc((size_t)NSLOT * sizeof(float));
    int*    counts   = (int*)   alloc(E_NUM * sizeof(int));
    int*    offsets  = (int*)   alloc((E_NUM + 1) * sizeof(int));
    int*    cursor   = (int*)   alloc(E_NUM * sizeof(int));
    int*    perm_tok = (int*)   alloc((size_t)NSLOT * sizeof(int));
    float*  perm_w   = (float*) alloc((size_t)NSLOT * sizeof(float));
    ushort* xb       = (ushort*)alloc((size_t)N_TOK * C_DIM * 2);
    ushort* Xg       = (ushort*)alloc((size_t)(NSLOT + 128) * C_DIM * 2);
    ushort* sgw_t    = (ushort*)alloc((size_t)C_DIM * 2 * HS_SH * 2);
    ushort* sdw_t    = (ushort*)alloc((size_t)HS_SH * C_DIM * 2);
    ushort* egw_t    = (ushort*)alloc((size_t)E_NUM * C_DIM * 2 * H_EXP * 2);
    ushort* edw_t    = (ushort*)alloc((size_t)E_NUM * H_EXP * C_DIM * 2);
    ushort* Hs_b     = (ushort*)alloc((size_t)N_TOK * HS_SH * 2);
    ushort* He_b     = (ushort*)alloc((size_t)(NSLOT + 128) * H_EXP * 2);
    (void)ws_size; (void)in_sizes; (void)n_in; (void)out_size;

    // Routing (fp32, exact)
    router_kernel<<<N_TOK, 256, 0, stream>>>(x, gw, gb, topk_idx, topk_w);
    zero_counts_kernel<<<1, 64, 0, stream>>>(counts);
    count_kernel<<<(NSLOT + 255) / 256, 256, 0, stream>>>(topk_idx, counts);
    scan_kernel<<<1, 64, 0, stream>>>(counts, offsets, cursor);
    scatter_kernel<<<(NSLOT + 255) / 256, 256, 0, stream>>>(topk_idx, topk_w, cursor,
                                                            perm_tok, perm_w);

    // Conversions / transposes to bf16 B^T layouts
    convert_x_kernel<<<(N_TOK * C_DIM / 4) / 256, 256, 0, stream>>>(x, xb);
    gather_kernel<<<NSLOT, 256, 0, stream>>>(xb, perm_tok, Xg);
    transp_conv<C_DIM, 2 * HS_SH, HS_SH><<<dim3(2 * HS_SH / 32, C_DIM / 32, 1), dim3(32, 8), 0, stream>>>(sgw, sgw_t);
    transp_conv<HS_SH, C_DIM, 0>       <<<dim3(C_DIM / 32, HS_SH / 32, 1), dim3(32, 8), 0, stream>>>(sdw, sdw_t);
    transp_conv<C_DIM, 2 * H_EXP, H_EXP><<<dim3(2 * H_EXP / 32, C_DIM / 32, E_NUM), dim3(32, 8), 0, stream>>>(egw, egw_t);
    transp_conv<H_EXP, C_DIM, 0>       <<<dim3(C_DIM / 32, H_EXP / 32, E_NUM), dim3(32, 8), 0, stream>>>(edw, edw_t);

    // Shared expert (gemm2 plain-stores -> initializes out)
    swiglu_mfma<C_DIM, 2 * HS_SH, false><<<dim3(2 * HS_SH / 128, N_TOK / 128, 1), 256, 0, stream>>>(
        xb, sgw_t, Hs_b, nullptr);
    down_mfma<HS_SH, false><<<dim3(C_DIM / 128, N_TOK / 128, 1), 256, 0, stream>>>(
        Hs_b, sdw_t, out, nullptr, nullptr, nullptr);

    // Routed experts (grouped; blocks beyond an expert's count exit early)
    swiglu_mfma<C_DIM, 2 * H_EXP, true><<<dim3(2 * H_EXP / 128, N_TOK / 128, E_NUM), 256, 0, stream>>>(
        Xg, egw_t, He_b, offsets);
    down_mfma<H_EXP, true><<<dim3(C_DIM / 128, N_TOK / 128, E_NUM), 256, 0, stream>>>(
        He_b, edw_t, out, offsets, perm_tok, perm_w);
}

// Round 3
// 488.338 us; speedup vs baseline: 1.8066x; 1.4323x over previous
//
#include <hip/hip_runtime.h>
#include <hip/hip_bf16.h>
#include <math.h>

// Problem constants (B=1, T=2048)
#define N_TOK 2048
#define C_DIM 1024
#define E_NUM 32
#define TOPKK 4
#define H_EXP 512
#define HS_SH 1024
#define NSLOT (N_TOK * TOPKK)   // 8192

typedef __attribute__((ext_vector_type(8))) short short8;
typedef __attribute__((ext_vector_type(4))) float f32x4;

__device__ __forceinline__ ushort f2b(float f) {
    __hip_bfloat16 h = __float2bfloat16(f);   // RNE
    return *(ushort*)&h;
}
__device__ __forceinline__ float silu_f(float g) { return g / (1.f + __expf(-g)); }

// Direct global->LDS DMA, 16 B per lane. LDS dest = wave-uniform base + lane*16.
__device__ __forceinline__ void glds16(const ushort* g, ushort* l) {
    __builtin_amdgcn_global_load_lds(
        (const __attribute__((address_space(1))) unsigned int*)g,
        (__attribute__((address_space(3))) unsigned int*)l, 16, 0, 0);
}

// ---------------- Router (exact fp32) ----------------
__global__ __launch_bounds__(256) void router_kernel(
    const float* __restrict__ x, const float* __restrict__ gate_w,
    const float* __restrict__ gate_bias, int* __restrict__ topk_idx,
    float* __restrict__ topk_w)
{
    __shared__ float xs[C_DIM];
    __shared__ float part[8][E_NUM];
    __shared__ float scores[E_NUM];
    const int n = blockIdx.x;
    const int t = threadIdx.x;
    const float* xr = x + (size_t)n * C_DIM;
    for (int i = t; i < C_DIM; i += 256) xs[i] = xr[i];
    __syncthreads();
    const int e = t & 31, cp = t >> 5;
    float s = 0.f;
    for (int c = cp * 128; c < cp * 128 + 128; ++c)
        s += xs[c] * gate_w[c * E_NUM + e];
    part[cp][e] = s;
    __syncthreads();
    if (t < E_NUM) {
        float tot = 0.f;
        for (int i = 0; i < 8; ++i) tot += part[i][e];
        scores[e] = 1.f / (1.f + expf(-tot));
    }
    __syncthreads();
    if (t == 0) {
        bool used[E_NUM];
        for (int i = 0; i < E_NUM; ++i) used[i] = false;
        int idx[TOPKK]; float wv[TOPKK]; float wsum = 0.f;
        for (int k = 0; k < TOPKK; ++k) {
            float best = -INFINITY; int bi = 0;
            for (int ee = 0; ee < E_NUM; ++ee) {
                if (used[ee]) continue;
                float v = scores[ee] + gate_bias[ee];
                if (v > best) { best = v; bi = ee; }
            }
            used[bi] = true; idx[k] = bi; wv[k] = scores[bi]; wsum += scores[bi];
        }
        float inv = 1.0f / wsum;
        for (int k = 0; k < TOPKK; ++k) {
            topk_idx[n * TOPKK + k] = idx[k];
            topk_w[n * TOPKK + k] = wv[k] * inv;
        }
    }
}

__global__ void zero_counts_kernel(int* __restrict__ counts)
{
    if (threadIdx.x < E_NUM) counts[threadIdx.x] = 0;
}

__global__ void count_kernel(const int* __restrict__ topk_idx, int* __restrict__ counts)
{
    int i = blockIdx.x * blockDim.x + threadIdx.x;
    if (i < NSLOT) atomicAdd(&counts[topk_idx[i]], 1);
}

__global__ void scan_kernel(const int* __restrict__ counts, int* __restrict__ offsets,
                            int* __restrict__ cursor)
{
    if (threadIdx.x == 0) {
        int acc = 0;
        for (int e2 = 0; e2 < E_NUM; ++e2) { offsets[e2] = acc; cursor[e2] = acc; acc += counts[e2]; }
        offsets[E_NUM] = acc;
    }
}

__global__ void scatter_kernel(const int* __restrict__ topk_idx, const float* __restrict__ topk_w,
                               int* __restrict__ cursor, int* __restrict__ perm_token,
                               float* __restrict__ perm_w)
{
    int i = blockIdx.x * blockDim.x + threadIdx.x;
    if (i < NSLOT) {
        int e2 = topk_idx[i];
        int pos = atomicAdd(&cursor[e2], 1);
        perm_token[pos] = i / TOPKK;
        perm_w[pos] = topk_w[i];
    }
}

// ---------------- Conversion: x (fp32) -> xb (bf16) ----------------
__global__ __launch_bounds__(256) void convert_x_kernel(const float* __restrict__ x,
                                                        ushort* __restrict__ xb)
{
    int gid = blockIdx.x * 256 + threadIdx.x;
    const float4 v = *(const float4*)(x + (size_t)gid * 4);
    ushort4 o;
    o.x = f2b(v.x); o.y = f2b(v.y); o.z = f2b(v.z); o.w = f2b(v.w);
    *(ushort4*)(xb + (size_t)gid * 4) = o;
}

__global__ __launch_bounds__(256) void gather_kernel(const ushort* __restrict__ xb,
                                                     const int* __restrict__ perm_token,
                                                     ushort* __restrict__ Xg)
{
    const int slot = blockIdx.x;
    const int row = perm_token[slot];
    const int t = threadIdx.x;
    *(ushort4*)(Xg + (size_t)slot * C_DIM + t * 4) =
        *(const ushort4*)(xb + (size_t)row * C_DIM + t * 4);
}

// ---------------- Transpose+convert weights to bf16 N'xK (B^T) ----------------
// PAIR_H > 0: interleave y/g in 16-col groups (SwiGLU pairs land in adjacent n-tiles)
template<int K, int N, int PAIR_H>
__global__ __launch_bounds__(256) void transp_conv(const float* __restrict__ in,
                                                   ushort* __restrict__ out)
{
    const float* inp = in + (size_t)blockIdx.z * K * N;
    ushort* outp = out + (size_t)blockIdx.z * K * N;
    __shared__ float T[32][33];
    const int tx = threadIdx.x, ty = threadIdx.y;      // (32, 8)
    const int n0 = blockIdx.x * 32, k0 = blockIdx.y * 32;
#pragma unroll
    for (int r = 0; r < 4; ++r)
        T[ty + r * 8][tx] = inp[(size_t)(k0 + ty + r * 8) * N + n0 + tx];
    __syncthreads();
#pragma unroll
    for (int r = 0; r < 4; ++r) {
        int n = n0 + ty + r * 8;
        int np;
        if (PAIR_H > 0)
            np = (n < PAIR_H) ? ((n >> 4) * 32 + (n & 15))
                              : (((n - PAIR_H) >> 4) * 32 + 16 + ((n - PAIR_H) & 15));
        else
            np = n;
        outp[(size_t)np * K + k0 + tx] = f2b(T[tx][ty + r * 8]);
    }
}

// ---------------- bf16 MFMA GEMM, 128x128 tile, m97 structure ----------------
// LDS tiles 128x64 bf16 unpadded (global_load_lds requires it); bank conflicts
// broken by XOR-swizzling the 16B chunk index on the GLOBAL address side:
//   phys_chunk p at lds row r holds logical chunk p ^ (r&7).
template<int K, int NP, bool EXPERT>
__global__ __launch_bounds__(256, 3) void swiglu_mfma(
    const ushort* __restrict__ Ab, const ushort* __restrict__ Bt,
    ushort* __restrict__ Out, const int* __restrict__ offsets)
{
    constexpr int H = NP / 2;
    int base = 0, cnt = N_TOK;
    const ushort* Bp = Bt;
    if (EXPERT) {
        const int e = blockIdx.z;
        base = offsets[e]; cnt = offsets[e + 1] - base;
        Bp = Bt + (size_t)e * NP * K;
    }
    const int m0 = blockIdx.y * 128;
    if (m0 >= cnt) return;
    const int n0 = blockIdx.x * 128;
    const ushort* Ap = Ab + (size_t)base * K;
    ushort* O = Out + (size_t)base * H;

    __shared__ __align__(16) ushort S[2 * 128 * 64];   // 32 KB: As | Bs
    ushort* As = S;
    ushort* Bs = S + 128 * 64;

    const int t = threadIdx.x;
    const int lane = t & 63, wave = t >> 6;
    const int wr = wave >> 1, wc = wave & 1;
    const int quad = lane >> 4, l16 = lane & 15;
    const int srow = lane >> 3;                  // 0..7 within the wave's 8-row group
    const int schunk = (lane & 7) ^ srow;        // swizzled logical 16B-chunk

    f32x4 acc[4][4];
#pragma unroll
    for (int i = 0; i < 4; ++i)
#pragma unroll
        for (int j = 0; j < 4; ++j) acc[i][j] = (f32x4){0.f, 0.f, 0.f, 0.f};

    const ushort* Ag = Ap + (size_t)(m0 + wave * 8 + srow) * K + schunk * 8;
    const ushort* Bg = Bp + (size_t)(n0 + wave * 8 + srow) * K + schunk * 8;

    for (int k0 = 0; k0 < K; k0 += 64) {
        __syncthreads();                         // prev tile reads done
#pragma unroll
        for (int i = 0; i < 4; ++i) {
            glds16(Ag + (size_t)(i * 32) * K + k0, As + (wave * 8 + i * 32) * 64);
            glds16(Bg + (size_t)(i * 32) * K + k0, Bs + (wave * 8 + i * 32) * 64);
        }
        __syncthreads();                         // vmcnt(0) drain -> DMA visible
#pragma unroll
        for (int ks = 0; ks < 2; ++ks) {
            const int coff = (((ks * 4 + quad) ^ (l16 & 7)) << 3);
            short8 af[4], bfr[4];
#pragma unroll
            for (int i = 0; i < 4; ++i) {
                af[i]  = *(const short8*)(As + (wr * 64 + i * 16 + l16) * 64 + coff);
                bfr[i] = *(const short8*)(Bs + (wc * 64 + i * 16 + l16) * 64 + coff);
            }
#pragma unroll
            for (int tm = 0; tm < 4; ++tm)
#pragma unroll
                for (int tn = 0; tn < 4; ++tn)
                    acc[tm][tn] = __builtin_amdgcn_mfma_f32_16x16x32_bf16(
                        af[tm], bfr[tn], acc[tm][tn], 0, 0, 0);
        }
    }

    // Epilogue: SwiGLU pair-combine (tn even=y, odd=g), LDS transpose, 16B stores
    __syncthreads();
#pragma unroll
    for (int tm = 0; tm < 4; ++tm)
#pragma unroll
        for (int p = 0; p < 2; ++p)
#pragma unroll
            for (int r = 0; r < 4; ++r) {
                const int ml = wr * 64 + tm * 16 + quad * 4 + r;
                const int hl = wc * 32 + p * 16 + l16;
                const float y = acc[tm][2 * p][r];
                const float g = acc[tm][2 * p + 1][r];
                S[ml * 72 + hl] = f2b(silu_f(g) * y);    // view as [128][72]
            }
    __syncthreads();
#pragma unroll
    for (int i = 0; i < 4; ++i) {
        const int c = t + i * 256;
        const int row = c >> 3, col = (c & 7) * 8;
        if (m0 + row < cnt)
            *(float4*)(O + (size_t)(m0 + row) * H + (n0 >> 1) + col) =
                *(const float4*)(S + row * 72 + col);
    }
}

// Down-proj GEMM. Shared: plain store (initializes Out). Expert: weighted atomicAdd.
template<int K, bool EXPERT>
__global__ __launch_bounds__(256, 3) void down_mfma(
    const ushort* __restrict__ Ab, const ushort* __restrict__ Bt,
    float* __restrict__ Out, const int* __restrict__ offsets,
    const int* __restrict__ perm_tok, const float* __restrict__ perm_w)
{
    int base = 0, cnt = N_TOK;
    const ushort* Bp = Bt;
    if (EXPERT) {
        const int e = blockIdx.z;
        base = offsets[e]; cnt = offsets[e + 1] - base;
        Bp = Bt + (size_t)e * C_DIM * K;
    }
    const int m0 = blockIdx.y * 128;
    if (m0 >= cnt) return;
    const int n0 = blockIdx.x * 128;
    const ushort* Ap = Ab + (size_t)base * K;

    __shared__ __align__(16) ushort S[2 * 128 * 64];
    ushort* As = S;
    ushort* Bs = S + 128 * 64;

    const int t = threadIdx.x;
    const int lane = t & 63, wave = t >> 6;
    const int wr = wave >> 1, wc = wave & 1;
    const int quad = lane >> 4, l16 = lane & 15;
    const int srow = lane >> 3;
    const int schunk = (lane & 7) ^ srow;

    f32x4 acc[4][4];
#pragma unroll
    for (int i = 0; i < 4; ++i)
#pragma unroll
        for (int j = 0; j < 4; ++j) acc[i][j] = (f32x4){0.f, 0.f, 0.f, 0.f};

    const ushort* Ag = Ap + (size_t)(m0 + wave * 8 + srow) * K + schunk * 8;
    const ushort* Bg = Bp + (size_t)(n0 + wave * 8 + srow) * K + schunk * 8;

    for (int k0 = 0; k0 < K; k0 += 64) {
        __syncthreads();
#pragma unroll
        for (int i = 0; i < 4; ++i) {
            glds16(Ag + (size_t)(i * 32) * K + k0, As + (wave * 8 + i * 32) * 64);
            glds16(Bg + (size_t)(i * 32) * K + k0, Bs + (wave * 8 + i * 32) * 64);
        }
        __syncthreads();
#pragma unroll
        for (int ks = 0; ks < 2; ++ks) {
            const int coff = (((ks * 4 + quad) ^ (l16 & 7)) << 3);
            short8 af[4], bfr[4];
#pragma unroll
            for (int i = 0; i < 4; ++i) {
                af[i]  = *(const short8*)(As + (wr * 64 + i * 16 + l16) * 64 + coff);
                bfr[i] = *(const short8*)(Bs + (wc * 64 + i * 16 + l16) * 64 + coff);
            }
#pragma unroll
            for (int tm = 0; tm < 4; ++tm)
#pragma unroll
                for (int tn = 0; tn < 4; ++tn)
                    acc[tm][tn] = __builtin_amdgcn_mfma_f32_16x16x32_bf16(
                        af[tm], bfr[tn], acc[tm][tn], 0, 0, 0);
        }
    }

#pragma unroll
    for (int tm = 0; tm < 4; ++tm)
#pragma unroll
        for (int r = 0; r < 4; ++r) {
            const int grow = m0 + wr * 64 + tm * 16 + quad * 4 + r;
            if (EXPERT) {
                if (grow < cnt) {
                    const int tok = perm_tok[base + grow];
                    const float w = perm_w[base + grow];
#pragma unroll
                    for (int tn = 0; tn < 4; ++tn) {
                        const int col = n0 + wc * 64 + tn * 16 + l16;
                        atomicAdd(&Out[(size_t)tok * C_DIM + col], w * acc[tm][tn][r]);
                    }
                }
            } else {
#pragma unroll
                for (int tn = 0; tn < 4; ++tn) {
                    const int col = n0 + wc * 64 + tn * 16 + l16;
                    Out[(size_t)grow * C_DIM + col] = acc[tm][tn][r];
                }
            }
        }
}

extern "C" void kernel_launch(void* const* d_in, const int* in_sizes, int n_in,
                              void* d_out, int out_size, void* d_ws, size_t ws_size,
                              hipStream_t stream)
{
    const float* x   = (const float*)d_in[0];
    const float* gw  = (const float*)d_in[1];
    const float* gb  = (const float*)d_in[2];
    const float* sgw = (const float*)d_in[3];
    const float* sdw = (const float*)d_in[4];
    const float* egw = (const float*)d_in[5];
    const float* edw = (const float*)d_in[6];
    float* out = (float*)d_out;

    char* ws = (char*)d_ws;
    size_t off = 0;
    auto alloc = [&](size_t bytes) -> void* {
        void* p = ws + off;
        off = (off + bytes + 255) & ~(size_t)255;
        return p;
    };
    int*    topk_idx = (int*)   alloc((size_t)NSLOT * sizeof(int));
    float*  topk_w   = (float*) alloc((size_t)NSLOT * sizeof(float));
    int*    counts   = (int*)   alloc(E_NUM * sizeof(int));
    int*    offsets  = (int*)   alloc((E_NUM + 1) * sizeof(int));
    int*    cursor   = (int*)   alloc(E_NUM * sizeof(int));
    int*    perm_tok = (int*)   alloc((size_t)NSLOT * sizeof(int));
    float*  perm_w   = (float*) alloc((size_t)NSLOT * sizeof(float));
    ushort* xb       = (ushort*)alloc((size_t)N_TOK * C_DIM * 2);
    ushort* Xg       = (ushort*)alloc((size_t)(NSLOT + 128) * C_DIM * 2);
    ushort* sgw_t    = (ushort*)alloc((size_t)C_DIM * 2 * HS_SH * 2);
    ushort* sdw_t    = (ushort*)alloc((size_t)HS_SH * C_DIM * 2);
    ushort* egw_t    = (ushort*)alloc((size_t)E_NUM * C_DIM * 2 * H_EXP * 2);
    ushort* edw_t    = (ushort*)alloc((size_t)E_NUM * H_EXP * C_DIM * 2);
    ushort* Hs_b     = (ushort*)alloc((size_t)N_TOK * HS_SH * 2);
    ushort* He_b     = (ushort*)alloc((size_t)(NSLOT + 128) * H_EXP * 2);
    (void)ws_size; (void)in_sizes; (void)n_in; (void)out_size;

    // Routing (fp32, exact)
    router_kernel<<<N_TOK, 256, 0, stream>>>(x, gw, gb, topk_idx, topk_w);
    zero_counts_kernel<<<1, 64, 0, stream>>>(counts);
    count_kernel<<<(NSLOT + 255) / 256, 256, 0, stream>>>(topk_idx, counts);
    scan_kernel<<<1, 64, 0, stream>>>(counts, offsets, cursor);
    scatter_kernel<<<(NSLOT + 255) / 256, 256, 0, stream>>>(topk_idx, topk_w, cursor,
                                                            perm_tok, perm_w);

    // Conversions / transposes to bf16 B^T layouts
    convert_x_kernel<<<(N_TOK * C_DIM / 4) / 256, 256, 0, stream>>>(x, xb);
    gather_kernel<<<NSLOT, 256, 0, stream>>>(xb, perm_tok, Xg);
    transp_conv<C_DIM, 2 * HS_SH, HS_SH><<<dim3(2 * HS_SH / 32, C_DIM / 32, 1), dim3(32, 8), 0, stream>>>(sgw, sgw_t);
    transp_conv<HS_SH, C_DIM, 0>       <<<dim3(C_DIM / 32, HS_SH / 32, 1), dim3(32, 8), 0, stream>>>(sdw, sdw_t);
    transp_conv<C_DIM, 2 * H_EXP, H_EXP><<<dim3(2 * H_EXP / 32, C_DIM / 32, E_NUM), dim3(32, 8), 0, stream>>>(egw, egw_t);
    transp_conv<H_EXP, C_DIM, 0>       <<<dim3(C_DIM / 32, H_EXP / 32, E_NUM), dim3(32, 8), 0, stream>>>(edw, edw_t);

    // Shared expert (gemm2 plain-stores -> initializes out)
    swiglu_mfma<C_DIM, 2 * HS_SH, false><<<dim3(2 * HS_SH / 128, N_TOK / 128, 1), 256, 0, stream>>>(
        xb, sgw_t, Hs_b, nullptr);
    down_mfma<HS_SH, false><<<dim3(C_DIM / 128, N_TOK / 128, 1), 256, 0, stream>>>(
        Hs_b, sdw_t, out, nullptr, nullptr, nullptr);

    // Routed experts (grouped; blocks beyond an expert's count exit early)
    swiglu_mfma<C_DIM, 2 * H_EXP, true><<<dim3(2 * H_EXP / 128, N_TOK / 128, E_NUM), 256, 0, stream>>>(
        Xg, egw_t, He_b, offsets);
    down_mfma<H_EXP, true><<<dim3(C_DIM / 128, N_TOK / 128, E_NUM), 256, 0, stream>>>(
        He_b, edw_t, out, offsets, perm_tok, perm_w);
}

// Round 4
// 466.823 us; speedup vs baseline: 1.8898x; 1.0461x over previous
//
#include <hip/hip_runtime.h>
#include <hip/hip_bf16.h>
#include <math.h>

// Problem constants (B=1, T=2048)
#define N_TOK 2048
#define C_DIM 1024
#define E_NUM 32
#define TOPKK 4
#define H_EXP 512
#define HS_SH 1024
#define NSLOT (N_TOK * TOPKK)   // 8192

typedef __attribute__((ext_vector_type(8))) short short8;
typedef __attribute__((ext_vector_type(4))) float f32x4;

__device__ __forceinline__ ushort f2b(float f) {
    __hip_bfloat16 h = __float2bfloat16(f);   // RNE
    return *(ushort*)&h;
}
__device__ __forceinline__ float silu_f(float g) { return g / (1.f + __expf(-g)); }

// Direct global->LDS DMA, 16 B per lane. Global src is PER-LANE; LDS dest = uniform base + lane*16.
__device__ __forceinline__ void glds16(const ushort* g, ushort* l) {
    __builtin_amdgcn_global_load_lds(
        (const __attribute__((address_space(1))) unsigned int*)g,
        (__attribute__((address_space(3))) unsigned int*)l, 16, 0, 0);
}

// ---------------- Router (exact fp32) ----------------
__global__ __launch_bounds__(256) void router_kernel(
    const float* __restrict__ x, const float* __restrict__ gate_w,
    const float* __restrict__ gate_bias, int* __restrict__ topk_idx,
    float* __restrict__ topk_w)
{
    __shared__ float xs[C_DIM];
    __shared__ float part[8][E_NUM];
    __shared__ float scores[E_NUM];
    const int n = blockIdx.x;
    const int t = threadIdx.x;
    const float* xr = x + (size_t)n * C_DIM;
    for (int i = t; i < C_DIM; i += 256) xs[i] = xr[i];
    __syncthreads();
    const int e = t & 31, cp = t >> 5;
    float s = 0.f;
    for (int c = cp * 128; c < cp * 128 + 128; ++c)
        s += xs[c] * gate_w[c * E_NUM + e];
    part[cp][e] = s;
    __syncthreads();
    if (t < E_NUM) {
        float tot = 0.f;
        for (int i = 0; i < 8; ++i) tot += part[i][e];
        scores[e] = 1.f / (1.f + expf(-tot));
    }
    __syncthreads();
    if (t == 0) {
        bool used[E_NUM];
        for (int i = 0; i < E_NUM; ++i) used[i] = false;
        int idx[TOPKK]; float wv[TOPKK]; float wsum = 0.f;
        for (int k = 0; k < TOPKK; ++k) {
            float best = -INFINITY; int bi = 0;
            for (int ee = 0; ee < E_NUM; ++ee) {
                if (used[ee]) continue;
                float v = scores[ee] + gate_bias[ee];
                if (v > best) { best = v; bi = ee; }
            }
            used[bi] = true; idx[k] = bi; wv[k] = scores[bi]; wsum += scores[bi];
        }
        float inv = 1.0f / wsum;
        for (int k = 0; k < TOPKK; ++k) {
            topk_idx[n * TOPKK + k] = idx[k];
            topk_w[n * TOPKK + k] = wv[k] * inv;
        }
    }
}

__global__ void zero_counts_kernel(int* __restrict__ counts)
{
    if (threadIdx.x < E_NUM) counts[threadIdx.x] = 0;
}

__global__ void count_kernel(const int* __restrict__ topk_idx, int* __restrict__ counts)
{
    int i = blockIdx.x * blockDim.x + threadIdx.x;
    if (i < NSLOT) atomicAdd(&counts[topk_idx[i]], 1);
}

__global__ void scan_kernel(const int* __restrict__ counts, int* __restrict__ offsets,
                            int* __restrict__ cursor)
{
    if (threadIdx.x == 0) {
        int acc = 0;
        for (int e2 = 0; e2 < E_NUM; ++e2) { offsets[e2] = acc; cursor[e2] = acc; acc += counts[e2]; }
        offsets[E_NUM] = acc;
    }
}

// Also records inv_slot: token-slot i -> permuted position (for the combine pass)
__global__ void scatter_kernel(const int* __restrict__ topk_idx, const float* __restrict__ topk_w,
                               int* __restrict__ cursor, int* __restrict__ perm_token,
                               float* __restrict__ perm_w, int* __restrict__ inv_slot)
{
    int i = blockIdx.x * blockDim.x + threadIdx.x;
    if (i < NSLOT) {
        int e2 = topk_idx[i];
        int pos = atomicAdd(&cursor[e2], 1);
        perm_token[pos] = i / TOPKK;
        perm_w[pos] = topk_w[i];
        inv_slot[i] = pos;
    }
}

// ---------------- Conversion: x (fp32) -> xb (bf16) ----------------
__global__ __launch_bounds__(256) void convert_x_kernel(const float* __restrict__ x,
                                                        ushort* __restrict__ xb)
{
    int gid = blockIdx.x * 256 + threadIdx.x;
    const float4 v = *(const float4*)(x + (size_t)gid * 4);
    ushort4 o;
    o.x = f2b(v.x); o.y = f2b(v.y); o.z = f2b(v.z); o.w = f2b(v.w);
    *(ushort4*)(xb + (size_t)gid * 4) = o;
}

// ---------------- Transpose+convert weights to bf16 N'xK (B^T), vectorized ----------------
// 32k x 64n tiles; float4 global loads, ushort8 global stores.
// PAIR_H > 0: interleave y/g in 16-col groups (SwiGLU pairs land in adjacent n-tiles)
template<int K, int N, int PAIR_H>
__global__ __launch_bounds__(256) void transp_conv(const float* __restrict__ in,
                                                   ushort* __restrict__ out)
{
    const float* inp = in + (size_t)blockIdx.z * K * N;
    ushort* outp = out + (size_t)blockIdx.z * K * N;
    __shared__ float T[32][65];
    const int t = threadIdx.x;
    const int k0 = blockIdx.y * 32, n0 = blockIdx.x * 64;
    {
        const int row = t >> 4;          // 0..15
        const int c4  = (t & 15) * 4;    // 0..60
#pragma unroll
        for (int i = 0; i < 2; ++i) {
            float4 v = *(const float4*)(inp + (size_t)(k0 + row + i * 16) * N + n0 + c4);
            T[row + i * 16][c4 + 0] = v.x; T[row + i * 16][c4 + 1] = v.y;
            T[row + i * 16][c4 + 2] = v.z; T[row + i * 16][c4 + 3] = v.w;
        }
    }
    __syncthreads();
    {
        const int n = t >> 2, kg = t & 3;   // n 0..63, k-group-of-8
        short8 o;
#pragma unroll
        for (int j = 0; j < 8; ++j) o[j] = (short)f2b(T[kg * 8 + j][n]);
        const int gn = n0 + n;
        int np;
        if (PAIR_H > 0)
            np = (gn < PAIR_H) ? ((gn >> 4) * 32 + (gn & 15))
                               : (((gn - PAIR_H) >> 4) * 32 + 16 + ((gn - PAIR_H) & 15));
        else
            np = gn;
        *(short8*)(outp + (size_t)np * K + k0 + kg * 8) = o;
    }
}

// ---------------- bf16 MFMA GEMM, 128x128 tile, m97 structure ----------------
// LDS tiles 128x64 bf16 unpadded (global_load_lds); bank conflicts broken by
// XOR-swizzling the 16B chunk index on the GLOBAL address side.
// EXPERT: A rows gathered through perm_tok (per-lane global addresses).
template<int K, int NP, bool EXPERT>
__global__ __launch_bounds__(256, 3) void swiglu_mfma(
    const ushort* __restrict__ Ab, const ushort* __restrict__ Bt,
    ushort* __restrict__ Out, const int* __restrict__ offsets,
    const int* __restrict__ perm_tok)
{
    constexpr int H = NP / 2;
    int base = 0, cnt = N_TOK;
    const ushort* Bp = Bt;
    if (EXPERT) {
        const int e = blockIdx.z;
        base = offsets[e]; cnt = offsets[e + 1] - base;
        Bp = Bt + (size_t)e * NP * K;
    }
    const int m0 = blockIdx.y * 128;
    if (m0 >= cnt) return;
    const int n0 = blockIdx.x * 128;
    ushort* O = Out + (size_t)base * H;

    __shared__ __align__(16) ushort S[2 * 128 * 64];   // 32 KB: As | Bs
    ushort* As = S;
    ushort* Bs = S + 128 * 64;

    const int t = threadIdx.x;
    const int lane = t & 63, wave = t >> 6;
    const int wr = wave >> 1, wc = wave & 1;
    const int quad = lane >> 4, l16 = lane & 15;
    const int srow = lane >> 3;                  // 0..7 within the wave's 8-row group
    const int schunk = (lane & 7) ^ srow;        // swizzled logical 16B-chunk

    f32x4 acc[4][4];
#pragma unroll
    for (int i = 0; i < 4; ++i)
#pragma unroll
        for (int j = 0; j < 4; ++j) acc[i][j] = (f32x4){0.f, 0.f, 0.f, 0.f};

    // Per-lane A source pointers (gathered rows for EXPERT)
    const ushort* AgI[4];
#pragma unroll
    for (int i = 0; i < 4; ++i) {
        int ar = m0 + wave * 8 + srow + i * 32;
        if (EXPERT) {
            ar = ar < cnt ? ar : 0;
            AgI[i] = Ab + (size_t)perm_tok[base + ar] * K + schunk * 8;
        } else {
            AgI[i] = Ab + (size_t)(base + ar) * K + schunk * 8;
        }
    }
    const ushort* Bg = Bp + (size_t)(n0 + wave * 8 + srow) * K + schunk * 8;

    for (int k0 = 0; k0 < K; k0 += 64) {
        __syncthreads();                         // prev tile reads done
#pragma unroll
        for (int i = 0; i < 4; ++i) {
            glds16(AgI[i] + k0, As + (wave * 8 + i * 32) * 64);
            glds16(Bg + (size_t)(i * 32) * K + k0, Bs + (wave * 8 + i * 32) * 64);
        }
        __syncthreads();                         // vmcnt(0) drain -> DMA visible
#pragma unroll
        for (int ks = 0; ks < 2; ++ks) {
            const int coff = (((ks * 4 + quad) ^ (l16 & 7)) << 3);
            short8 af[4], bfr[4];
#pragma unroll
            for (int i = 0; i < 4; ++i) {
                af[i]  = *(const short8*)(As + (wr * 64 + i * 16 + l16) * 64 + coff);
                bfr[i] = *(const short8*)(Bs + (wc * 64 + i * 16 + l16) * 64 + coff);
            }
#pragma unroll
            for (int tm = 0; tm < 4; ++tm)
#pragma unroll
                for (int tn = 0; tn < 4; ++tn)
                    acc[tm][tn] = __builtin_amdgcn_mfma_f32_16x16x32_bf16(
                        af[tm], bfr[tn], acc[tm][tn], 0, 0, 0);
        }
    }

    // Epilogue: SwiGLU pair-combine (tn even=y, odd=g), LDS transpose, 16B stores
    __syncthreads();
#pragma unroll
    for (int tm = 0; tm < 4; ++tm)
#pragma unroll
        for (int p = 0; p < 2; ++p)
#pragma unroll
            for (int r = 0; r < 4; ++r) {
                const int ml = wr * 64 + tm * 16 + quad * 4 + r;
                const int hl = wc * 32 + p * 16 + l16;
                const float y = acc[tm][2 * p][r];
                const float g = acc[tm][2 * p + 1][r];
                S[ml * 72 + hl] = f2b(silu_f(g) * y);    // view as [128][72]
            }
    __syncthreads();
#pragma unroll
    for (int i = 0; i < 4; ++i) {
        const int c = t + i * 256;
        const int row = c >> 3, col = (c & 7) * 8;
        if (m0 + row < cnt)
            *(float4*)(O + (size_t)(m0 + row) * H + (n0 >> 1) + col) =
                *(const float4*)(S + row * 72 + col);
    }
}

// Down-proj GEMM. Shared: plain store into Out. Expert: streaming store of
// w*acc into per-slot buffer Ye (combined later; no atomics).
template<int K, bool EXPERT>
__global__ __launch_bounds__(256, 3) void down_mfma(
    const ushort* __restrict__ Ab, const ushort* __restrict__ Bt,
    float* __restrict__ Out, const int* __restrict__ offsets,
    const float* __restrict__ perm_w)
{
    int base = 0, cnt = N_TOK;
    const ushort* Bp = Bt;
    if (EXPERT) {
        const int e = blockIdx.z;
        base = offsets[e]; cnt = offsets[e + 1] - base;
        Bp = Bt + (size_t)e * C_DIM * K;
    }
    const int m0 = blockIdx.y * 128;
    if (m0 >= cnt) return;
    const int n0 = blockIdx.x * 128;
    const ushort* Ap = Ab + (size_t)base * K;

    __shared__ __align__(16) ushort S[2 * 128 * 64];
    ushort* As = S;
    ushort* Bs = S + 128 * 64;

    const int t = threadIdx.x;
    const int lane = t & 63, wave = t >> 6;
    const int wr = wave >> 1, wc = wave & 1;
    const int quad = lane >> 4, l16 = lane & 15;
    const int srow = lane >> 3;
    const int schunk = (lane & 7) ^ srow;

    f32x4 acc[4][4];
#pragma unroll
    for (int i = 0; i < 4; ++i)
#pragma unroll
        for (int j = 0; j < 4; ++j) acc[i][j] = (f32x4){0.f, 0.f, 0.f, 0.f};

    const ushort* Ag = Ap + (size_t)(m0 + wave * 8 + srow) * K + schunk * 8;
    const ushort* Bg = Bp + (size_t)(n0 + wave * 8 + srow) * K + schunk * 8;

    for (int k0 = 0; k0 < K; k0 += 64) {
        __syncthreads();
#pragma unroll
        for (int i = 0; i < 4; ++i) {
            glds16(Ag + (size_t)(i * 32) * K + k0, As + (wave * 8 + i * 32) * 64);
            glds16(Bg + (size_t)(i * 32) * K + k0, Bs + (wave * 8 + i * 32) * 64);
        }
        __syncthreads();
#pragma unroll
        for (int ks = 0; ks < 2; ++ks) {
            const int coff = (((ks * 4 + quad) ^ (l16 & 7)) << 3);
            short8 af[4], bfr[4];
#pragma unroll
            for (int i = 0; i < 4; ++i) {
                af[i]  = *(const short8*)(As + (wr * 64 + i * 16 + l16) * 64 + coff);
                bfr[i] = *(const short8*)(Bs + (wc * 64 + i * 16 + l16) * 64 + coff);
            }
#pragma unroll
            for (int tm = 0; tm < 4; ++tm)
#pragma unroll
                for (int tn = 0; tn < 4; ++tn)
                    acc[tm][tn] = __builtin_amdgcn_mfma_f32_16x16x32_bf16(
                        af[tm], bfr[tn], acc[tm][tn], 0, 0, 0);
        }
    }

#pragma unroll
    for (int tm = 0; tm < 4; ++tm)
#pragma unroll
        for (int r = 0; r < 4; ++r) {
            const int grow = m0 + wr * 64 + tm * 16 + quad * 4 + r;
            if (EXPERT) {
                if (grow < cnt) {
                    const float w = perm_w[base + grow];
#pragma unroll
                    for (int tn = 0; tn < 4; ++tn) {
                        const int col = n0 + wc * 64 + tn * 16 + l16;
                        Out[(size_t)(base + grow) * C_DIM + col] = w * acc[tm][tn][r];
                    }
                }
            } else {
#pragma unroll
                for (int tn = 0; tn < 4; ++tn) {
                    const int col = n0 + wc * 64 + tn * 16 + l16;
                    Out[(size_t)grow * C_DIM + col] = acc[tm][tn][r];
                }
            }
        }
}

// out[token] += sum_k Ye[slot_k(token)]   (shared result already in out)
__global__ __launch_bounds__(256) void combine_kernel(
    const float* __restrict__ Ye, const int* __restrict__ inv_slot,
    float* __restrict__ Out)
{
    const int tok = blockIdx.x;
    __shared__ int s4[TOPKK];
    if (threadIdx.x < TOPKK) s4[threadIdx.x] = inv_slot[tok * TOPKK + threadIdx.x];
    __syncthreads();
    const int c = threadIdx.x * 4;
    float4 acc = *(const float4*)(Out + (size_t)tok * C_DIM + c);
#pragma unroll
    for (int k = 0; k < TOPKK; ++k) {
        float4 v = *(const float4*)(Ye + (size_t)s4[k] * C_DIM + c);
        acc.x += v.x; acc.y += v.y; acc.z += v.z; acc.w += v.w;
    }
    *(float4*)(Out + (size_t)tok * C_DIM + c) = acc;
}

extern "C" void kernel_launch(void* const* d_in, const int* in_sizes, int n_in,
                              void* d_out, int out_size, void* d_ws, size_t ws_size,
                              hipStream_t stream)
{
    const float* x   = (const float*)d_in[0];
    const float* gw  = (const float*)d_in[1];
    const float* gb  = (const float*)d_in[2];
    const float* sgw = (const float*)d_in[3];
    const float* sdw = (const float*)d_in[4];
    const float* egw = (const float*)d_in[5];
    const float* edw = (const float*)d_in[6];
    float* out = (float*)d_out;

    char* ws = (char*)d_ws;
    size_t off = 0;
    auto alloc = [&](size_t bytes) -> void* {
        void* p = ws + off;
        off = (off + bytes + 255) & ~(size_t)255;
        return p;
    };
    int*    topk_idx = (int*)   alloc((size_t)NSLOT * sizeof(int));
    float*  topk_w   = (float*) alloc((size_t)NSLOT * sizeof(float));
    int*    counts   = (int*)   alloc(E_NUM * sizeof(int));
    int*    offsets  = (int*)   alloc((E_NUM + 1) * sizeof(int));
    int*    cursor   = (int*)   alloc(E_NUM * sizeof(int));
    int*    perm_tok = (int*)   alloc((size_t)NSLOT * sizeof(int));
    float*  perm_w   = (float*) alloc((size_t)NSLOT * sizeof(float));
    int*    inv_slot = (int*)   alloc((size_t)NSLOT * sizeof(int));
    ushort* xb       = (ushort*)alloc((size_t)N_TOK * C_DIM * 2);
    ushort* sgw_t    = (ushort*)alloc((size_t)C_DIM * 2 * HS_SH * 2);
    ushort* sdw_t    = (ushort*)alloc((size_t)HS_SH * C_DIM * 2);
    ushort* egw_t    = (ushort*)alloc((size_t)E_NUM * C_DIM * 2 * H_EXP * 2);
    ushort* edw_t    = (ushort*)alloc((size_t)E_NUM * H_EXP * C_DIM * 2);
    ushort* Hs_b     = (ushort*)alloc((size_t)N_TOK * HS_SH * 2);
    ushort* He_b     = (ushort*)alloc((size_t)(NSLOT + 128) * H_EXP * 2);
    float*  Ye       = (float*) alloc((size_t)(NSLOT + 128) * C_DIM * sizeof(float));
    (void)ws_size; (void)in_sizes; (void)n_in; (void)out_size;

    // Routing (fp32, exact)
    router_kernel<<<N_TOK, 256, 0, stream>>>(x, gw, gb, topk_idx, topk_w);
    zero_counts_kernel<<<1, 64, 0, stream>>>(counts);
    count_kernel<<<(NSLOT + 255) / 256, 256, 0, stream>>>(topk_idx, counts);
    scan_kernel<<<1, 64, 0, stream>>>(counts, offsets, cursor);
    scatter_kernel<<<(NSLOT + 255) / 256, 256, 0, stream>>>(topk_idx, topk_w, cursor,
                                                            perm_tok, perm_w, inv_slot);

    // Conversions / transposes to bf16 B^T layouts
    convert_x_kernel<<<(N_TOK * C_DIM / 4) / 256, 256, 0, stream>>>(x, xb);
    transp_conv<C_DIM, 2 * HS_SH, HS_SH><<<dim3(2 * HS_SH / 64, C_DIM / 32, 1), 256, 0, stream>>>(sgw, sgw_t);
    transp_conv<HS_SH, C_DIM, 0>       <<<dim3(C_DIM / 64, HS_SH / 32, 1), 256, 0, stream>>>(sdw, sdw_t);
    transp_conv<C_DIM, 2 * H_EXP, H_EXP><<<dim3(2 * H_EXP / 64, C_DIM / 32, E_NUM), 256, 0, stream>>>(egw, egw_t);
    transp_conv<H_EXP, C_DIM, 0>       <<<dim3(C_DIM / 64, H_EXP / 32, E_NUM), 256, 0, stream>>>(edw, edw_t);

    // Shared expert (down plain-stores -> initializes out)
    swiglu_mfma<C_DIM, 2 * HS_SH, false><<<dim3(2 * HS_SH / 128, N_TOK / 128, 1), 256, 0, stream>>>(
        xb, sgw_t, Hs_b, nullptr, nullptr);
    down_mfma<HS_SH, false><<<dim3(C_DIM / 128, N_TOK / 128, 1), 256, 0, stream>>>(
        Hs_b, sdw_t, out, nullptr, nullptr);

    // Routed experts (grouped; A gathered in-kernel via perm_tok)
    swiglu_mfma<C_DIM, 2 * H_EXP, true><<<dim3(2 * H_EXP / 128, N_TOK / 128, E_NUM), 256, 0, stream>>>(
        xb, egw_t, He_b, offsets, perm_tok);
    down_mfma<H_EXP, true><<<dim3(C_DIM / 128, N_TOK / 128, E_NUM), 256, 0, stream>>>(
        He_b, edw_t, Ye, offsets, perm_w);

    // Final combine: out += sum of this token's 4 expert slots
    combine_kernel<<<N_TOK, 256, 0, stream>>>(Ye, inv_slot, out);
}

// Round 5
// 435.897 us; speedup vs baseline: 2.0239x; 1.0709x over previous
//
#include <hip/hip_runtime.h>
#include <hip/hip_bf16.h>
#include <math.h>

// Problem constants (B=1, T=2048)
#define N_TOK 2048
#define C_DIM 1024
#define E_NUM 32
#define TOPKK 4
#define H_EXP 512
#define HS_SH 1024
#define NSLOT (N_TOK * TOPKK)   // 8192

typedef __attribute__((ext_vector_type(8))) short short8;
typedef __attribute__((ext_vector_type(4))) float f32x4;

__device__ __forceinline__ ushort f2b(float f) {
    __hip_bfloat16 h = __float2bfloat16(f);   // RNE
    return *(ushort*)&h;
}
__device__ __forceinline__ float silu_f(float g) { return g / (1.f + __expf(-g)); }

// Direct global->LDS DMA, 16 B per lane. Global src is PER-LANE; LDS dest = uniform base + lane*16.
__device__ __forceinline__ void glds16(const ushort* g, ushort* l) {
    __builtin_amdgcn_global_load_lds(
        (const __attribute__((address_space(1))) unsigned int*)g,
        (__attribute__((address_space(3))) unsigned int*)l, 16, 0, 0);
}

// ---------------- Router: scores + shuffle top-k (no scratch arrays) ----------------
// Also converts this token's x row to bf16 (fuses convert_x).
__global__ __launch_bounds__(256) void router_kernel(
    const float* __restrict__ x, const float* __restrict__ gate_w,
    const float* __restrict__ gate_bias, ushort* __restrict__ xb,
    int* __restrict__ topk_idx, float* __restrict__ topk_w)
{
    __shared__ float xs[C_DIM];
    __shared__ float part[8][E_NUM];
    __shared__ float scores_s[E_NUM];
    const int n = blockIdx.x;
    const int t = threadIdx.x;
    const float* xr = x + (size_t)n * C_DIM;
    {   // load x row + bf16 convert (256 threads * 4 = 1024)
        float4 v = ((const float4*)xr)[t];
        xs[t * 4 + 0] = v.x; xs[t * 4 + 1] = v.y;
        xs[t * 4 + 2] = v.z; xs[t * 4 + 3] = v.w;
        ushort4 o;
        o.x = f2b(v.x); o.y = f2b(v.y); o.z = f2b(v.z); o.w = f2b(v.w);
        ((ushort4*)(xb + (size_t)n * C_DIM))[t] = o;
    }
    __syncthreads();
    const int e = t & 31, cp = t >> 5;
    float s = 0.f;
#pragma unroll 4
    for (int c = cp * 128; c < cp * 128 + 128; ++c)
        s += xs[c] * gate_w[c * E_NUM + e];
    part[cp][e] = s;
    __syncthreads();
    if (t < E_NUM) {
        float tot = 0.f;
#pragma unroll
        for (int i = 0; i < 8; ++i) tot += part[i][t];
        scores_s[t] = 1.f / (1.f + expf(-tot));
    }
    __syncthreads();
    if (t < 64) {   // wave 0: register top-k via shuffle/ballot
        const int l = t;
        const float sc  = (l < E_NUM) ? scores_s[l] : -INFINITY;
        const float scb = (l < E_NUM) ? sc + gate_bias[l] : -INFINITY;
        bool used = false;
        int myidx[TOPKK]; float myw[TOPKK]; float wsum = 0.f;
#pragma unroll
        for (int k = 0; k < TOPKK; ++k) {
            float v = used ? -INFINITY : scb;
            float m = v;
#pragma unroll
            for (int d = 1; d < 64; d <<= 1) m = fmaxf(m, __shfl_xor(m, d));
            unsigned long long b = __ballot(v == m);
            const int pick = __ffsll((unsigned long long)b) - 1;  // lowest index on tie
            if (l == pick) used = true;
            const float w = __shfl(sc, pick);
            myidx[k] = pick; myw[k] = w; wsum += w;
        }
        if (l == 0) {
            const float inv = 1.0f / wsum;   // ROUTE_SCALE = 1.0
#pragma unroll
            for (int k = 0; k < TOPKK; ++k) {
                topk_idx[n * TOPKK + k] = myidx[k];
                topk_w[n * TOPKK + k] = myw[k] * inv;
            }
        }
    }
}

// ---------------- Routing meta: count + scan + scatter, one block ----------------
__global__ __launch_bounds__(1024) void route_build(
    const int* __restrict__ topk_idx, const float* __restrict__ topk_w,
    int* __restrict__ offsets, int* __restrict__ perm_token,
    float* __restrict__ perm_w, int* __restrict__ inv_slot)
{
    __shared__ int cnt[E_NUM];
    __shared__ int off_s[E_NUM + 1];
    const int t = threadIdx.x;
    if (t < E_NUM) cnt[t] = 0;
    __syncthreads();
    int myidx[8];
#pragma unroll
    for (int j = 0; j < 8; ++j) {
        const int i = t * 8 + j;
        myidx[j] = topk_idx[i];
        atomicAdd(&cnt[myidx[j]], 1);
    }
    __syncthreads();
    if (t == 0) {
        int a = 0;
        for (int e2 = 0; e2 < E_NUM; ++e2) { off_s[e2] = a; a += cnt[e2]; }
        off_s[E_NUM] = a;
    }
    __syncthreads();
    if (t < E_NUM) cnt[t] = off_s[t];          // reuse as cursor
    if (t <= E_NUM) offsets[t] = off_s[t];
    __syncthreads();
#pragma unroll
    for (int j = 0; j < 8; ++j) {
        const int i = t * 8 + j;
        const int pos = atomicAdd(&cnt[myidx[j]], 1);
        perm_token[pos] = i >> 2;
        perm_w[pos] = topk_w[i];
        inv_slot[i] = pos;
    }
}

// ---------------- Transpose+convert weights to bf16 N'xK (B^T), 64x64 tiles ----------------
// PAIR_H > 0: interleave y/g in 16-col groups (SwiGLU pairs land in adjacent n-tiles)
template<int K, int N, int PAIR_H>
__global__ __launch_bounds__(256) void transp_conv(const float* __restrict__ in,
                                                   ushort* __restrict__ out)
{
    const float* inp = in + (size_t)blockIdx.z * K * N;
    ushort* outp = out + (size_t)blockIdx.z * K * N;
    __shared__ float T[64][68];
    const int t = threadIdx.x;
    const int k0 = blockIdx.y * 64, n0 = blockIdx.x * 64;
    {
        const int row = t >> 4;          // 0..15
        const int c4  = (t & 15) * 4;    // 0..60
#pragma unroll
        for (int i = 0; i < 4; ++i) {
            float4 v = *(const float4*)(inp + (size_t)(k0 + row + i * 16) * N + n0 + c4);
            T[row + i * 16][c4 + 0] = v.x; T[row + i * 16][c4 + 1] = v.y;
            T[row + i * 16][c4 + 2] = v.z; T[row + i * 16][c4 + 3] = v.w;
        }
    }
    __syncthreads();
    {
        const int nn = t & 63, kg = t >> 6;   // nn 0..63, kg 0..3 (16 k each)
        const int gn = n0 + nn;
        int np;
        if (PAIR_H > 0)
            np = (gn < PAIR_H) ? ((gn >> 4) * 32 + (gn & 15))
                               : (((gn - PAIR_H) >> 4) * 32 + 16 + ((gn - PAIR_H) & 15));
        else
            np = gn;
#pragma unroll
        for (int half = 0; half < 2; ++half) {
            const int k8 = kg * 16 + half * 8;
            short8 o;
#pragma unroll
            for (int j = 0; j < 8; ++j) o[j] = (short)f2b(T[k8 + j][nn]);
            *(short8*)(outp + (size_t)np * K + k0 + k8) = o;
        }
    }
}

// ---------------- bf16 MFMA GEMM, 128x128 tile, m97 structure ----------------
// LDS tiles 128x64 bf16 unpadded (global_load_lds); bank conflicts broken by
// XOR-swizzling the 16B chunk index on the GLOBAL address side.
// EXPERT: A rows gathered through perm_tok (per-lane global addresses).
template<int K, int NP, bool EXPERT>
__global__ __launch_bounds__(256, 3) void swiglu_mfma(
    const ushort* __restrict__ Ab, const ushort* __restrict__ Bt,
    ushort* __restrict__ Out, const int* __restrict__ offsets,
    const int* __restrict__ perm_tok)
{
    constexpr int H = NP / 2;
    int base = 0, cnt = N_TOK;
    const ushort* Bp = Bt;
    if (EXPERT) {
        const int e = blockIdx.z;
        base = offsets[e]; cnt = offsets[e + 1] - base;
        Bp = Bt + (size_t)e * NP * K;
    }
    const int m0 = blockIdx.y * 128;
    if (m0 >= cnt) return;
    const int n0 = blockIdx.x * 128;
    ushort* O = Out + (size_t)base * H;

    __shared__ __align__(16) ushort S[2 * 128 * 64];   // 32 KB: As | Bs
    ushort* As = S;
    ushort* Bs = S + 128 * 64;

    const int t = threadIdx.x;
    const int lane = t & 63, wave = t >> 6;
    const int wr = wave >> 1, wc = wave & 1;
    const int quad = lane >> 4, l16 = lane & 15;
    const int srow = lane >> 3;                  // 0..7 within the wave's 8-row group
    const int schunk = (lane & 7) ^ srow;        // swizzled logical 16B-chunk

    f32x4 acc[4][4];
#pragma unroll
    for (int i = 0; i < 4; ++i)
#pragma unroll
        for (int j = 0; j < 4; ++j) acc[i][j] = (f32x4){0.f, 0.f, 0.f, 0.f};

    const ushort* AgI[4];
#pragma unroll
    for (int i = 0; i < 4; ++i) {
        int ar = m0 + wave * 8 + srow + i * 32;
        if (EXPERT) {
            ar = ar < cnt ? ar : 0;
            AgI[i] = Ab + (size_t)perm_tok[base + ar] * K + schunk * 8;
        } else {
            AgI[i] = Ab + (size_t)(base + ar) * K + schunk * 8;
        }
    }
    const ushort* Bg = Bp + (size_t)(n0 + wave * 8 + srow) * K + schunk * 8;

    for (int k0 = 0; k0 < K; k0 += 64) {
        __syncthreads();                         // prev tile reads done
#pragma unroll
        for (int i = 0; i < 4; ++i) {
            glds16(AgI[i] + k0, As + (wave * 8 + i * 32) * 64);
            glds16(Bg + (size_t)(i * 32) * K + k0, Bs + (wave * 8 + i * 32) * 64);
        }
        __syncthreads();                         // vmcnt(0) drain -> DMA visible
#pragma unroll
        for (int ks = 0; ks < 2; ++ks) {
            const int coff = (((ks * 4 + quad) ^ (l16 & 7)) << 3);
            short8 af[4], bfr[4];
#pragma unroll
            for (int i = 0; i < 4; ++i) {
                af[i]  = *(const short8*)(As + (wr * 64 + i * 16 + l16) * 64 + coff);
                bfr[i] = *(const short8*)(Bs + (wc * 64 + i * 16 + l16) * 64 + coff);
            }
#pragma unroll
            for (int tm = 0; tm < 4; ++tm)
#pragma unroll
                for (int tn = 0; tn < 4; ++tn)
                    acc[tm][tn] = __builtin_amdgcn_mfma_f32_16x16x32_bf16(
                        af[tm], bfr[tn], acc[tm][tn], 0, 0, 0);
        }
    }

    // Epilogue: SwiGLU pair-combine (tn even=y, odd=g), LDS transpose, 16B stores
    __syncthreads();
#pragma unroll
    for (int tm = 0; tm < 4; ++tm)
#pragma unroll
        for (int p = 0; p < 2; ++p)
#pragma unroll
            for (int r = 0; r < 4; ++r) {
                const int ml = wr * 64 + tm * 16 + quad * 4 + r;
                const int hl = wc * 32 + p * 16 + l16;
                const float y = acc[tm][2 * p][r];
                const float g = acc[tm][2 * p + 1][r];
                S[ml * 72 + hl] = f2b(silu_f(g) * y);    // view as [128][72]
            }
    __syncthreads();
#pragma unroll
    for (int i = 0; i < 4; ++i) {
        const int c = t + i * 256;
        const int row = c >> 3, col = (c & 7) * 8;
        if (m0 + row < cnt)
            *(float4*)(O + (size_t)(m0 + row) * H + (n0 >> 1) + col) =
                *(const float4*)(S + row * 72 + col);
    }
}

// Down-proj GEMM. Shared: plain store into Out. Expert: streaming store of
// w*acc into per-slot buffer Ye (combined later; no atomics).
template<int K, bool EXPERT>
__global__ __launch_bounds__(256, 3) void down_mfma(
    const ushort* __restrict__ Ab, const ushort* __restrict__ Bt,
    float* __restrict__ Out, const int* __restrict__ offsets,
    const float* __restrict__ perm_w)
{
    int base = 0, cnt = N_TOK;
    const ushort* Bp = Bt;
    if (EXPERT) {
        const int e = blockIdx.z;
        base = offsets[e]; cnt = offsets[e + 1] - base;
        Bp = Bt + (size_t)e * C_DIM * K;
    }
    const int m0 = blockIdx.y * 128;
    if (m0 >= cnt) return;
    const int n0 = blockIdx.x * 128;
    const ushort* Ap = Ab + (size_t)base * K;

    __shared__ __align__(16) ushort S[2 * 128 * 64];
    ushort* As = S;
    ushort* Bs = S + 128 * 64;

    const int t = threadIdx.x;
    const int lane = t & 63, wave = t >> 6;
    const int wr = wave >> 1, wc = wave & 1;
    const int quad = lane >> 4, l16 = lane & 15;
    const int srow = lane >> 3;
    const int schunk = (lane & 7) ^ srow;

    f32x4 acc[4][4];
#pragma unroll
    for (int i = 0; i < 4; ++i)
#pragma unroll
        for (int j = 0; j < 4; ++j) acc[i][j] = (f32x4){0.f, 0.f, 0.f, 0.f};

    const ushort* Ag = Ap + (size_t)(m0 + wave * 8 + srow) * K + schunk * 8;
    const ushort* Bg = Bp + (size_t)(n0 + wave * 8 + srow) * K + schunk * 8;

    for (int k0 = 0; k0 < K; k0 += 64) {
        __syncthreads();
#pragma unroll
        for (int i = 0; i < 4; ++i) {
            glds16(Ag + (size_t)(i * 32) * K + k0, As + (wave * 8 + i * 32) * 64);
            glds16(Bg + (size_t)(i * 32) * K + k0, Bs + (wave * 8 + i * 32) * 64);
        }
        __syncthreads();
#pragma unroll
        for (int ks = 0; ks < 2; ++ks) {
            const int coff = (((ks * 4 + quad) ^ (l16 & 7)) << 3);
            short8 af[4], bfr[4];
#pragma unroll
            for (int i = 0; i < 4; ++i) {
                af[i]  = *(const short8*)(As + (wr * 64 + i * 16 + l16) * 64 + coff);
                bfr[i] = *(const short8*)(Bs + (wc * 64 + i * 16 + l16) * 64 + coff);
            }
#pragma unroll
            for (int tm = 0; tm < 4; ++tm)
#pragma unroll
                for (int tn = 0; tn < 4; ++tn)
                    acc[tm][tn] = __builtin_amdgcn_mfma_f32_16x16x32_bf16(
                        af[tm], bfr[tn], acc[tm][tn], 0, 0, 0);
        }
    }

#pragma unroll
    for (int tm = 0; tm < 4; ++tm)
#pragma unroll
        for (int r = 0; r < 4; ++r) {
            const int grow = m0 + wr * 64 + tm * 16 + quad * 4 + r;
            if (EXPERT) {
                if (grow < cnt) {
                    const float w = perm_w[base + grow];
#pragma unroll
                    for (int tn = 0; tn < 4; ++tn) {
                        const int col = n0 + wc * 64 + tn * 16 + l16;
                        Out[(size_t)(base + grow) * C_DIM + col] = w * acc[tm][tn][r];
                    }
                }
            } else {
#pragma unroll
                for (int tn = 0; tn < 4; ++tn) {
                    const int col = n0 + wc * 64 + tn * 16 + l16;
                    Out[(size_t)grow * C_DIM + col] = acc[tm][tn][r];
                }
            }
        }
}

// out[token] += sum_k Ye[slot_k(token)]   (shared result already in out)
__global__ __launch_bounds__(256) void combine_kernel(
    const float* __restrict__ Ye, const int* __restrict__ inv_slot,
    float* __restrict__ Out)
{
    const int tok = blockIdx.x;
    __shared__ int s4[TOPKK];
    if (threadIdx.x < TOPKK) s4[threadIdx.x] = inv_slot[tok * TOPKK + threadIdx.x];
    __syncthreads();
    const int c = threadIdx.x * 4;
    float4 acc = *(const float4*)(Out + (size_t)tok * C_DIM + c);
#pragma unroll
    for (int k = 0; k < TOPKK; ++k) {
        float4 v = *(const float4*)(Ye + (size_t)s4[k] * C_DIM + c);
        acc.x += v.x; acc.y += v.y; acc.z += v.z; acc.w += v.w;
    }
    *(float4*)(Out + (size_t)tok * C_DIM + c) = acc;
}

extern "C" void kernel_launch(void* const* d_in, const int* in_sizes, int n_in,
                              void* d_out, int out_size, void* d_ws, size_t ws_size,
                              hipStream_t stream)
{
    const float* x   = (const float*)d_in[0];
    const float* gw  = (const float*)d_in[1];
    const float* gb  = (const float*)d_in[2];
    const float* sgw = (const float*)d_in[3];
    const float* sdw = (const float*)d_in[4];
    const float* egw = (const float*)d_in[5];
    const float* edw = (const float*)d_in[6];
    float* out = (float*)d_out;

    char* ws = (char*)d_ws;
    size_t off = 0;
    auto alloc = [&](size_t bytes) -> void* {
        void* p = ws + off;
        off = (off + bytes + 255) & ~(size_t)255;
        return p;
    };
    int*    topk_idx = (int*)   alloc((size_t)NSLOT * sizeof(int));
    float*  topk_w   = (float*) alloc((size_t)NSLOT * sizeof(float));
    int*    offsets  = (int*)   alloc((E_NUM + 1) * sizeof(int));
    int*    perm_tok = (int*)   alloc((size_t)NSLOT * sizeof(int));
    float*  perm_w   = (float*) alloc((size_t)NSLOT * sizeof(float));
    int*    inv_slot = (int*)   alloc((size_t)NSLOT * sizeof(int));
    ushort* xb       = (ushort*)alloc((size_t)N_TOK * C_DIM * 2);
    ushort* sgw_t    = (ushort*)alloc((size_t)C_DIM * 2 * HS_SH * 2);
    ushort* sdw_t    = (ushort*)alloc((size_t)HS_SH * C_DIM * 2);
    ushort* egw_t    = (ushort*)alloc((size_t)E_NUM * C_DIM * 2 * H_EXP * 2);
    ushort* edw_t    = (ushort*)alloc((size_t)E_NUM * H_EXP * C_DIM * 2);
    ushort* Hs_b     = (ushort*)alloc((size_t)N_TOK * HS_SH * 2);
    ushort* He_b     = (ushort*)alloc((size_t)(NSLOT + 128) * H_EXP * 2);
    float*  Ye       = (float*) alloc((size_t)(NSLOT + 128) * C_DIM * sizeof(float));
    (void)ws_size; (void)in_sizes; (void)n_in; (void)out_size;

    // Routing (fp32 scores, shuffle top-k) + fused x->bf16 conversion
    router_kernel<<<N_TOK, 256, 0, stream>>>(x, gw, gb, xb, topk_idx, topk_w);
    route_build<<<1, 1024, 0, stream>>>(topk_idx, topk_w, offsets, perm_tok, perm_w, inv_slot);

    // Weight transposes/conversions to bf16 B^T layouts
    transp_conv<C_DIM, 2 * HS_SH, HS_SH><<<dim3(2 * HS_SH / 64, C_DIM / 64, 1), 256, 0, stream>>>(sgw, sgw_t);
    transp_conv<HS_SH, C_DIM, 0>       <<<dim3(C_DIM / 64, HS_SH / 64, 1), 256, 0, stream>>>(sdw, sdw_t);
    transp_conv<C_DIM, 2 * H_EXP, H_EXP><<<dim3(2 * H_EXP / 64, C_DIM / 64, E_NUM), 256, 0, stream>>>(egw, egw_t);
    transp_conv<H_EXP, C_DIM, 0>       <<<dim3(C_DIM / 64, H_EXP / 64, E_NUM), 256, 0, stream>>>(edw, edw_t);

    // Shared expert (down plain-stores -> initializes out)
    swiglu_mfma<C_DIM, 2 * HS_SH, false><<<dim3(2 * HS_SH / 128, N_TOK / 128, 1), 256, 0, stream>>>(
        xb, sgw_t, Hs_b, nullptr, nullptr);
    down_mfma<HS_SH, false><<<dim3(C_DIM / 128, N_TOK / 128, 1), 256, 0, stream>>>(
        Hs_b, sdw_t, out, nullptr, nullptr);

    // Routed experts (grouped; A gathered in-kernel via perm_tok)
    swiglu_mfma<C_DIM, 2 * H_EXP, true><<<dim3(2 * H_EXP / 128, N_TOK / 128, E_NUM), 256, 0, stream>>>(
        xb, egw_t, He_b, offsets, perm_tok);
    down_mfma<H_EXP, true><<<dim3(C_DIM / 128, N_TOK / 128, E_NUM), 256, 0, stream>>>(
        He_b, edw_t, Ye, offsets, perm_w);

    // Final combine: out += sum of this token's 4 expert slots
    combine_kernel<<<N_TOK, 256, 0, stream>>>(Ye, inv_slot, out);
}

// Round 6
// 428.871 us; speedup vs baseline: 2.0571x; 1.0164x over previous
//
#include <hip/hip_runtime.h>
#include <hip/hip_bf16.h>
#include <math.h>

// Problem constants (B=1, T=2048)
#define N_TOK 2048
#define C_DIM 1024
#define E_NUM 32
#define TOPKK 4
#define H_EXP 512
#define HS_SH 1024
#define NSLOT (N_TOK * TOPKK)   // 8192

typedef __attribute__((ext_vector_type(8))) short short8;
typedef __attribute__((ext_vector_type(4))) float f32x4;

__device__ __forceinline__ ushort f2b(float f) {
    __hip_bfloat16 h = __float2bfloat16(f);   // RNE
    return *(ushort*)&h;
}
__device__ __forceinline__ float silu_f(float g) { return g / (1.f + __expf(-g)); }

// Direct global->LDS DMA, 16 B per lane. Global src is PER-LANE; LDS dest = uniform base + lane*16.
__device__ __forceinline__ void glds16(const ushort* g, ushort* l) {
    __builtin_amdgcn_global_load_lds(
        (const __attribute__((address_space(1))) unsigned int*)g,
        (__attribute__((address_space(3))) unsigned int*)l, 16, 0, 0);
}

// ---------------- Router: scores + shuffle top-k (no scratch arrays) ----------------
// Also converts this token's x row to bf16 (fuses convert_x).
__global__ __launch_bounds__(256) void router_kernel(
    const float* __restrict__ x, const float* __restrict__ gate_w,
    const float* __restrict__ gate_bias, ushort* __restrict__ xb,
    int* __restrict__ topk_idx, float* __restrict__ topk_w)
{
    __shared__ float xs[C_DIM];
    __shared__ float part[8][E_NUM];
    __shared__ float scores_s[E_NUM];
    const int n = blockIdx.x;
    const int t = threadIdx.x;
    const float* xr = x + (size_t)n * C_DIM;
    {   // load x row + bf16 convert (256 threads * 4 = 1024)
        float4 v = ((const float4*)xr)[t];
        xs[t * 4 + 0] = v.x; xs[t * 4 + 1] = v.y;
        xs[t * 4 + 2] = v.z; xs[t * 4 + 3] = v.w;
        ushort4 o;
        o.x = f2b(v.x); o.y = f2b(v.y); o.z = f2b(v.z); o.w = f2b(v.w);
        ((ushort4*)(xb + (size_t)n * C_DIM))[t] = o;
    }
    __syncthreads();
    const int e = t & 31, cp = t >> 5;
    float s = 0.f;
#pragma unroll 4
    for (int c = cp * 128; c < cp * 128 + 128; ++c)
        s += xs[c] * gate_w[c * E_NUM + e];
    part[cp][e] = s;
    __syncthreads();
    if (t < E_NUM) {
        float tot = 0.f;
#pragma unroll
        for (int i = 0; i < 8; ++i) tot += part[i][t];
        scores_s[t] = 1.f / (1.f + expf(-tot));
    }
    __syncthreads();
    if (t < 64) {   // wave 0: register top-k via shuffle/ballot
        const int l = t;
        const float sc  = (l < E_NUM) ? scores_s[l] : -INFINITY;
        const float scb = (l < E_NUM) ? sc + gate_bias[l] : -INFINITY;
        bool used = false;
        int myidx[TOPKK]; float myw[TOPKK]; float wsum = 0.f;
#pragma unroll
        for (int k = 0; k < TOPKK; ++k) {
            float v = used ? -INFINITY : scb;
            float m = v;
#pragma unroll
            for (int d = 1; d < 64; d <<= 1) m = fmaxf(m, __shfl_xor(m, d));
            unsigned long long b = __ballot(v == m);
            const int pick = __ffsll((unsigned long long)b) - 1;  // lowest index on tie
            if (l == pick) used = true;
            const float w = __shfl(sc, pick);
            myidx[k] = pick; myw[k] = w; wsum += w;
        }
        if (l == 0) {
            const float inv = 1.0f / wsum;   // ROUTE_SCALE = 1.0
#pragma unroll
            for (int k = 0; k < TOPKK; ++k) {
                topk_idx[n * TOPKK + k] = myidx[k];
                topk_w[n * TOPKK + k] = myw[k] * inv;
            }
        }
    }
}

// ---------------- Routing meta: count + scan + scatter, one block ----------------
__global__ __launch_bounds__(1024) void route_build(
    const int* __restrict__ topk_idx, const float* __restrict__ topk_w,
    int* __restrict__ offsets, int* __restrict__ perm_token,
    float* __restrict__ perm_w, int* __restrict__ inv_slot)
{
    __shared__ int cnt[E_NUM];
    __shared__ int off_s[E_NUM + 1];
    const int t = threadIdx.x;
    if (t < E_NUM) cnt[t] = 0;
    __syncthreads();
    int myidx[8];
#pragma unroll
    for (int j = 0; j < 8; ++j) {
        const int i = t * 8 + j;
        myidx[j] = topk_idx[i];
        atomicAdd(&cnt[myidx[j]], 1);
    }
    __syncthreads();
    if (t == 0) {
        int a = 0;
        for (int e2 = 0; e2 < E_NUM; ++e2) { off_s[e2] = a; a += cnt[e2]; }
        off_s[E_NUM] = a;
    }
    __syncthreads();
    if (t < E_NUM) cnt[t] = off_s[t];          // reuse as cursor
    if (t <= E_NUM) offsets[t] = off_s[t];
    __syncthreads();
#pragma unroll
    for (int j = 0; j < 8; ++j) {
        const int i = t * 8 + j;
        const int pos = atomicAdd(&cnt[myidx[j]], 1);
        perm_token[pos] = i >> 2;
        perm_w[pos] = topk_w[i];
        inv_slot[i] = pos;
    }
}

// ---------------- Transpose+convert weights to bf16 N'xK (B^T), 64x64 tiles ----------------
// Store phase: 8 lanes cooperate per output row -> 128 B contiguous global writes
// (16 txns/wave vs 64 for row-per-lane). LDS T[64][65]: read bank = (8*kg + j + nn)%32,
// wave covers all 32 banks 2x -> free.
// PAIR_H > 0: interleave y/g in 16-col groups (SwiGLU pairs land in adjacent n-tiles)
template<int K, int N, int PAIR_H>
__global__ __launch_bounds__(256) void transp_conv(const float* __restrict__ in,
                                                   ushort* __restrict__ out)
{
    const float* inp = in + (size_t)blockIdx.z * K * N;
    ushort* outp = out + (size_t)blockIdx.z * K * N;
    __shared__ float T[64][65];
    const int t = threadIdx.x;
    const int k0 = blockIdx.y * 64, n0 = blockIdx.x * 64;
    {
        const int row = t >> 4;          // 0..15
        const int c4  = (t & 15) * 4;    // 0..60
#pragma unroll
        for (int i = 0; i < 4; ++i) {
            float4 v = *(const float4*)(inp + (size_t)(k0 + row + i * 16) * N + n0 + c4);
            T[row + i * 16][c4 + 0] = v.x; T[row + i * 16][c4 + 1] = v.y;
            T[row + i * 16][c4 + 2] = v.z; T[row + i * 16][c4 + 3] = v.w;
        }
    }
    __syncthreads();
    {
        const int g  = t >> 3;           // 0..31: row-group
        const int kg = t & 7;            // 0..7 : 8-k chunk within the 64-k tile
#pragma unroll
        for (int p = 0; p < 2; ++p) {
            const int nn = p * 32 + g;
            const int gn = n0 + nn;
            int np;
            if (PAIR_H > 0)
                np = (gn < PAIR_H) ? ((gn >> 4) * 32 + (gn & 15))
                                   : (((gn - PAIR_H) >> 4) * 32 + 16 + ((gn - PAIR_H) & 15));
            else
                np = gn;
            short8 o;
#pragma unroll
            for (int j = 0; j < 8; ++j) o[j] = (short)f2b(T[kg * 8 + j][nn]);
            *(short8*)(outp + (size_t)np * K + k0 + kg * 8) = o;
        }
    }
}

// ---------------- bf16 MFMA GEMM, 128x128 tile, m97 structure ----------------
// LDS tiles 128x64 bf16 unpadded (global_load_lds); bank conflicts broken by
// XOR-swizzling the 16B chunk index on the GLOBAL address side.
// EXPERT: A rows gathered through perm_tok (per-lane global addresses).
template<int K, int NP, bool EXPERT>
__global__ __launch_bounds__(256, 3) void swiglu_mfma(
    const ushort* __restrict__ Ab, const ushort* __restrict__ Bt,
    ushort* __restrict__ Out, const int* __restrict__ offsets,
    const int* __restrict__ perm_tok)
{
    constexpr int H = NP / 2;
    int base = 0, cnt = N_TOK;
    const ushort* Bp = Bt;
    if (EXPERT) {
        const int e = blockIdx.z;
        base = offsets[e]; cnt = offsets[e + 1] - base;
        Bp = Bt + (size_t)e * NP * K;
    }
    const int m0 = blockIdx.y * 128;
    if (m0 >= cnt) return;
    const int n0 = blockIdx.x * 128;
    ushort* O = Out + (size_t)base * H;

    __shared__ __align__(16) ushort S[2 * 128 * 64];   // 32 KB: As | Bs
    ushort* As = S;
    ushort* Bs = S + 128 * 64;

    const int t = threadIdx.x;
    const int lane = t & 63, wave = t >> 6;
    const int wr = wave >> 1, wc = wave & 1;
    const int quad = lane >> 4, l16 = lane & 15;
    const int srow = lane >> 3;                  // 0..7 within the wave's 8-row group
    const int schunk = (lane & 7) ^ srow;        // swizzled logical 16B-chunk

    f32x4 acc[4][4];
#pragma unroll
    for (int i = 0; i < 4; ++i)
#pragma unroll
        for (int j = 0; j < 4; ++j) acc[i][j] = (f32x4){0.f, 0.f, 0.f, 0.f};

    const ushort* AgI[4];
#pragma unroll
    for (int i = 0; i < 4; ++i) {
        int ar = m0 + wave * 8 + srow + i * 32;
        if (EXPERT) {
            ar = ar < cnt ? ar : 0;
            AgI[i] = Ab + (size_t)perm_tok[base + ar] * K + schunk * 8;
        } else {
            AgI[i] = Ab + (size_t)(base + ar) * K + schunk * 8;
        }
    }
    const ushort* Bg = Bp + (size_t)(n0 + wave * 8 + srow) * K + schunk * 8;

    for (int k0 = 0; k0 < K; k0 += 64) {
        __syncthreads();                         // prev tile reads done
#pragma unroll
        for (int i = 0; i < 4; ++i) {
            glds16(AgI[i] + k0, As + (wave * 8 + i * 32) * 64);
            glds16(Bg + (size_t)(i * 32) * K + k0, Bs + (wave * 8 + i * 32) * 64);
        }
        __syncthreads();                         // vmcnt(0) drain -> DMA visible
#pragma unroll
        for (int ks = 0; ks < 2; ++ks) {
            const int coff = (((ks * 4 + quad) ^ (l16 & 7)) << 3);
            short8 af[4], bfr[4];
#pragma unroll
            for (int i = 0; i < 4; ++i) {
                af[i]  = *(const short8*)(As + (wr * 64 + i * 16 + l16) * 64 + coff);
                bfr[i] = *(const short8*)(Bs + (wc * 64 + i * 16 + l16) * 64 + coff);
            }
#pragma unroll
            for (int tm = 0; tm < 4; ++tm)
#pragma unroll
                for (int tn = 0; tn < 4; ++tn)
                    acc[tm][tn] = __builtin_amdgcn_mfma_f32_16x16x32_bf16(
                        af[tm], bfr[tn], acc[tm][tn], 0, 0, 0);
        }
    }

    // Epilogue: SwiGLU pair-combine (tn even=y, odd=g), LDS transpose, 16B stores
    __syncthreads();
#pragma unroll
    for (int tm = 0; tm < 4; ++tm)
#pragma unroll
        for (int p = 0; p < 2; ++p)
#pragma unroll
            for (int r = 0; r < 4; ++r) {
                const int ml = wr * 64 + tm * 16 + quad * 4 + r;
                const int hl = wc * 32 + p * 16 + l16;
                const float y = acc[tm][2 * p][r];
                const float g = acc[tm][2 * p + 1][r];
                S[ml * 72 + hl] = f2b(silu_f(g) * y);    // view as [128][72]
            }
    __syncthreads();
#pragma unroll
    for (int i = 0; i < 4; ++i) {
        const int c = t + i * 256;
        const int row = c >> 3, col = (c & 7) * 8;
        if (m0 + row < cnt)
            *(float4*)(O + (size_t)(m0 + row) * H + (n0 >> 1) + col) =
                *(const float4*)(S + row * 72 + col);
    }
}

// Down-proj GEMM. Shared: plain store into Out. Expert: streaming store of
// w*acc into per-slot buffer Ye (combined later; no atomics).
template<int K, bool EXPERT>
__global__ __launch_bounds__(256, 3) void down_mfma(
    const ushort* __restrict__ Ab, const ushort* __restrict__ Bt,
    float* __restrict__ Out, const int* __restrict__ offsets,
    const float* __restrict__ perm_w)
{
    int base = 0, cnt = N_TOK;
    const ushort* Bp = Bt;
    if (EXPERT) {
        const int e = blockIdx.z;
        base = offsets[e]; cnt = offsets[e + 1] - base;
        Bp = Bt + (size_t)e * C_DIM * K;
    }
    const int m0 = blockIdx.y * 128;
    if (m0 >= cnt) return;
    const int n0 = blockIdx.x * 128;
    const ushort* Ap = Ab + (size_t)base * K;

    __shared__ __align__(16) ushort S[2 * 128 * 64];
    ushort* As = S;
    ushort* Bs = S + 128 * 64;

    const int t = threadIdx.x;
    const int lane = t & 63, wave = t >> 6;
    const int wr = wave >> 1, wc = wave & 1;
    const int quad = lane >> 4, l16 = lane & 15;
    const int srow = lane >> 3;
    const int schunk = (lane & 7) ^ srow;

    f32x4 acc[4][4];
#pragma unroll
    for (int i = 0; i < 4; ++i)
#pragma unroll
        for (int j = 0; j < 4; ++j) acc[i][j] = (f32x4){0.f, 0.f, 0.f, 0.f};

    const ushort* Ag = Ap + (size_t)(m0 + wave * 8 + srow) * K + schunk * 8;
    const ushort* Bg = Bp + (size_t)(n0 + wave * 8 + srow) * K + schunk * 8;

    for (int k0 = 0; k0 < K; k0 += 64) {
        __syncthreads();
#pragma unroll
        for (int i = 0; i < 4; ++i) {
            glds16(Ag + (size_t)(i * 32) * K + k0, As + (wave * 8 + i * 32) * 64);
            glds16(Bg + (size_t)(i * 32) * K + k0, Bs + (wave * 8 + i * 32) * 64);
        }
        __syncthreads();
#pragma unroll
        for (int ks = 0; ks < 2; ++ks) {
            const int coff = (((ks * 4 + quad) ^ (l16 & 7)) << 3);
            short8 af[4], bfr[4];
#pragma unroll
            for (int i = 0; i < 4; ++i) {
                af[i]  = *(const short8*)(As + (wr * 64 + i * 16 + l16) * 64 + coff);
                bfr[i] = *(const short8*)(Bs + (wc * 64 + i * 16 + l16) * 64 + coff);
            }
#pragma unroll
            for (int tm = 0; tm < 4; ++tm)
#pragma unroll
                for (int tn = 0; tn < 4; ++tn)
                    acc[tm][tn] = __builtin_amdgcn_mfma_f32_16x16x32_bf16(
                        af[tm], bfr[tn], acc[tm][tn], 0, 0, 0);
        }
    }

#pragma unroll
    for (int tm = 0; tm < 4; ++tm)
#pragma unroll
        for (int r = 0; r < 4; ++r) {
            const int grow = m0 + wr * 64 + tm * 16 + quad * 4 + r;
            if (EXPERT) {
                if (grow < cnt) {
                    const float w = perm_w[base + grow];
#pragma unroll
                    for (int tn = 0; tn < 4; ++tn) {
                        const int col = n0 + wc * 64 + tn * 16 + l16;
                        Out[(size_t)(base + grow) * C_DIM + col] = w * acc[tm][tn][r];
                    }
                }
            } else {
#pragma unroll
                for (int tn = 0; tn < 4; ++tn) {
                    const int col = n0 + wc * 64 + tn * 16 + l16;
                    Out[(size_t)grow * C_DIM + col] = acc[tm][tn][r];
                }
            }
        }
}

// out[token] += sum_k Ye[slot_k(token)]   (shared result already in out)
__global__ __launch_bounds__(256) void combine_kernel(
    const float* __restrict__ Ye, const int* __restrict__ inv_slot,
    float* __restrict__ Out)
{
    const int tok = blockIdx.x;
    __shared__ int s4[TOPKK];
    if (threadIdx.x < TOPKK) s4[threadIdx.x] = inv_slot[tok * TOPKK + threadIdx.x];
    __syncthreads();
    const int c = threadIdx.x * 4;
    float4 acc = *(const float4*)(Out + (size_t)tok * C_DIM + c);
#pragma unroll
    for (int k = 0; k < TOPKK; ++k) {
        float4 v = *(const float4*)(Ye + (size_t)s4[k] * C_DIM + c);
        acc.x += v.x; acc.y += v.y; acc.z += v.z; acc.w += v.w;
    }
    *(float4*)(Out + (size_t)tok * C_DIM + c) = acc;
}

extern "C" void kernel_launch(void* const* d_in, const int* in_sizes, int n_in,
                              void* d_out, int out_size, void* d_ws, size_t ws_size,
                              hipStream_t stream)
{
    const float* x   = (const float*)d_in[0];
    const float* gw  = (const float*)d_in[1];
    const float* gb  = (const float*)d_in[2];
    const float* sgw = (const float*)d_in[3];
    const float* sdw = (const float*)d_in[4];
    const float* egw = (const float*)d_in[5];
    const float* edw = (const float*)d_in[6];
    float* out = (float*)d_out;

    char* ws = (char*)d_ws;
    size_t off = 0;
    auto alloc = [&](size_t bytes) -> void* {
        void* p = ws + off;
        off = (off + bytes + 255) & ~(size_t)255;
        return p;
    };
    int*    topk_idx = (int*)   alloc((size_t)NSLOT * sizeof(int));
    float*  topk_w   = (float*) alloc((size_t)NSLOT * sizeof(float));
    int*    offsets  = (int*)   alloc((E_NUM + 1) * sizeof(int));
    int*    perm_tok = (int*)   alloc((size_t)NSLOT * sizeof(int));
    float*  perm_w   = (float*) alloc((size_t)NSLOT * sizeof(float));
    int*    inv_slot = (int*)   alloc((size_t)NSLOT * sizeof(int));
    ushort* xb       = (ushort*)alloc((size_t)N_TOK * C_DIM * 2);
    ushort* sgw_t    = (ushort*)alloc((size_t)C_DIM * 2 * HS_SH * 2);
    ushort* sdw_t    = (ushort*)alloc((size_t)HS_SH * C_DIM * 2);
    ushort* egw_t    = (ushort*)alloc((size_t)E_NUM * C_DIM * 2 * H_EXP * 2);
    ushort* edw_t    = (ushort*)alloc((size_t)E_NUM * H_EXP * C_DIM * 2);
    ushort* Hs_b     = (ushort*)alloc((size_t)N_TOK * HS_SH * 2);
    ushort* He_b     = (ushort*)alloc((size_t)(NSLOT + 128) * H_EXP * 2);
    float*  Ye       = (float*) alloc((size_t)(NSLOT + 128) * C_DIM * sizeof(float));
    (void)ws_size; (void)in_sizes; (void)n_in; (void)out_size;

    // Routing (fp32 scores, shuffle top-k) + fused x->bf16 conversion
    router_kernel<<<N_TOK, 256, 0, stream>>>(x, gw, gb, xb, topk_idx, topk_w);
    route_build<<<1, 1024, 0, stream>>>(topk_idx, topk_w, offsets, perm_tok, perm_w, inv_slot);

    // Weight transposes/conversions to bf16 B^T layouts (coalesced 128B stores)
    transp_conv<C_DIM, 2 * HS_SH, HS_SH><<<dim3(2 * HS_SH / 64, C_DIM / 64, 1), 256, 0, stream>>>(sgw, sgw_t);
    transp_conv<HS_SH, C_DIM, 0>       <<<dim3(C_DIM / 64, HS_SH / 64, 1), 256, 0, stream>>>(sdw, sdw_t);
    transp_conv<C_DIM, 2 * H_EXP, H_EXP><<<dim3(2 * H_EXP / 64, C_DIM / 64, E_NUM), 256, 0, stream>>>(egw, egw_t);
    transp_conv<H_EXP, C_DIM, 0>       <<<dim3(C_DIM / 64, H_EXP / 64, E_NUM), 256, 0, stream>>>(edw, edw_t);

    // Shared expert (down plain-stores -> initializes out)
    swiglu_mfma<C_DIM, 2 * HS_SH, false><<<dim3(2 * HS_SH / 128, N_TOK / 128, 1), 256, 0, stream>>>(
        xb, sgw_t, Hs_b, nullptr, nullptr);
    down_mfma<HS_SH, false><<<dim3(C_DIM / 128, N_TOK / 128, 1), 256, 0, stream>>>(
        Hs_b, sdw_t, out, nullptr, nullptr);

    // Routed experts (grouped; A gathered in-kernel via perm_tok)
    swiglu_mfma<C_DIM, 2 * H_EXP, true><<<dim3(2 * H_EXP / 128, N_TOK / 128, E_NUM), 256, 0, stream>>>(
        xb, egw_t, He_b, offsets, perm_tok);
    down_mfma<H_EXP, true><<<dim3(C_DIM / 128, N_TOK / 128, E_NUM), 256, 0, stream>>>(
        He_b, edw_t, Ye, offsets, perm_w);

    // Final combine: out += sum of this token's 4 expert slots
    combine_kernel<<<N_TOK, 256, 0, stream>>>(Ye, inv_slot, out);
}